// Round 8
// baseline (606.487 us; speedup 1.0000x reference)
//
#include <hip/hip_runtime.h>
#include <hip/hip_bf16.h>
#include <math.h>

// LSTM B=4096,T=3,I=16,H=512,L=8 + fc head.
// Round 14: B (weights) no longer passes through LDS. Each wave loads its
// B fragments directly global->VGPR from L2 (L2-resident via the 2D XCD
// mapping; coalesced 1KB segments; compiler emits precise per-reg vmcnt
// waits). LDS holds only the A double-buffer (16KB). LDS traffic per
// CU-slot drops 256KB -> 96KB, leaving MFMA as the long pole.
// Blocks: 256 threads / 4 waves (wave tile 32x64, block tile 64x128),
// __launch_bounds__(256,4) -> 4 blocks/CU, 16 waves. Grid 1024/cell,
// XCD map: 16 mhalves x 8 cols per XCD (A+B hot set << 4MB L2).
// Keeps: bank-swizzled packed layout (A LDS-read swizzle + B global-read
// swizzle consistent with prep), fast epilogue math, split-int8 MFMA,
// de-phase parity start, setprio. R13's s_sleep reverted (neutral).

#define BATCH 4096
#define TT 3
#define HH 512
#define LL 8

typedef __attribute__((ext_vector_type(4))) int   i32x4;

#define S_W 0.04419417382f                  // 1/sqrt(512), weight uniform bound
#define GSCALE   (S_W / 16129.0f)           // sW*sH = (S_W/127)*(1/127)
#define GSCALE_C (GSCALE / 128.0f)
#define C_SCALE   8192.0f
#define C_INV     (1.0f / 8192.0f)

__device__ inline void gl_lds16(const void* g, void* l) {
    __builtin_amdgcn_global_load_lds(
        (const __attribute__((address_space(1))) void*)g,
        (__attribute__((address_space(3))) void*)l, 16, 0, 0);
}

__device__ inline void q2i8(float v, float inv_s, signed char& h, signed char& l) {
    float q = v * inv_s;
    int ih = __float2int_rn(q);
    ih = ih > 127 ? 127 : (ih < -127 ? -127 : ih);
    float rem = q - (float)ih;
    int il = __float2int_rn(rem * 128.f);
    il = il > 127 ? 127 : (il < -127 ? -127 : il);
    h = (signed char)ih; l = (signed char)il;
}

__device__ inline float fsig(float x) {
    return __builtin_amdgcn_rcpf(1.f + __expf(-x));
}
__device__ inline float ftanh(float x) {
    const float e = __expf(-2.f * __builtin_fabsf(x));
    const float t = (1.f - e) * __builtin_amdgcn_rcpf(1.f + e);
    return __builtin_copysignf(t, x);
}

// ---------------- prep kernels ----------------
// Packed layout per matrix digit: [col=np>>7][kstep=k>>6][row=np&127][k&63]
// with 16B chunk c of row r stored at slot c ^ ((r>>1)&3)  (bank swizzle).

__global__ __launch_bounds__(256) void prep_w_i8(
    const float* __restrict__ Wihrest, const float* __restrict__ Whh,
    char* __restrict__ WihPh, char* __restrict__ WihPl,
    char* __restrict__ WhhPh, char* __restrict__ WhhPl)
{
    const int e = blockIdx.x * 256 + threadIdx.x;   // 15*2048*128 float4 units
    const int mat = e >> 18;
    const int rem = e & 262143;
    const int row = rem >> 7;            // 0..2047
    const int k4  = (rem & 127) << 2;    // 0..508
    const float* src; char *dh, *dl;
    if (mat < 7) {
        src = Wihrest + (size_t)mat * 1048576;
        dh = WihPh + (size_t)mat * 1048576;
        dl = WihPl + (size_t)mat * 1048576;
    } else {
        const int l = mat - 7;
        src = Whh + (size_t)l * 1048576;
        dh = WhhPh + (size_t)l * 1048576;
        dl = WhhPl + (size_t)l * 1048576;
    }
    const int q = row >> 9, j = row & 511;
    const int np = ((j >> 4) << 6) | (q << 4) | (j & 15);
    const int rw = np & 127;
    const int swz = ((rw >> 1) & 3) << 4;
    const size_t off = (size_t)(np >> 7) * 65536 + (size_t)(k4 >> 6) * 8192
                     + (size_t)rw * 64 + ((k4 & 63) ^ swz);
    const float4 v = *(const float4*)(src + (size_t)row * 512 + k4);
    const float inv = 127.0f / S_W;
    signed char h0,l0,h1,l1,h2,l2,h3,l3;
    q2i8(v.x, inv, h0, l0); q2i8(v.y, inv, h1, l1);
    q2i8(v.z, inv, h2, l2); q2i8(v.w, inv, h3, l3);
    unsigned hw = (unsigned char)h0 | ((unsigned char)h1 << 8) |
                  ((unsigned char)h2 << 16) | ((unsigned)(unsigned char)h3 << 24);
    unsigned lw = (unsigned char)l0 | ((unsigned char)l1 << 8) |
                  ((unsigned char)l2 << 16) | ((unsigned)(unsigned char)l3 << 24);
    *(unsigned*)(dh + off) = hw;
    *(unsigned*)(dl + off) = lw;
}

__global__ __launch_bounds__(256) void prep_w0_i8(
    const float* __restrict__ W0, char* __restrict__ Dh, char* __restrict__ Dl)
{
    const int row = blockIdx.x * 256 + threadIdx.x;
    if (row >= 2048) return;
    const int q = row >> 9, j = row & 511;
    const int np = ((j >> 4) << 6) | (q << 4) | (j & 15);
    const int sl = (np >> 1) & 3;
    const size_t off = (size_t)(np >> 7) * 8192 + (size_t)(np & 127) * 64;
    const float inv = 127.0f / S_W;
    signed char bh[64], bl[64];
#pragma unroll
    for (int k = 0; k < 16; ++k) q2i8(W0[(size_t)row * 16 + k], inv, bh[k], bl[k]);
#pragma unroll
    for (int k = 16; k < 64; ++k) { bh[k] = 0; bl[k] = 0; }
#pragma unroll
    for (int i = 0; i < 4; ++i) {
        *(int4*)(Dh + off + (i ^ sl) * 16) = *(int4*)(bh + i * 16);
        *(int4*)(Dl + off + (i ^ sl) * 16) = *(int4*)(bl + i * 16);
    }
}

__global__ __launch_bounds__(256) void prep_x_i8(
    const float* __restrict__ x, char* __restrict__ Xh, char* __restrict__ Xl)
{
    const int id = blockIdx.x * 256 + threadIdx.x;
    if (id >= TT * BATCH) return;
    const int t = id >> 12, b = id & 4095;
    const float* src = x + ((size_t)b * TT + t) * 16;
    const int sl = (b >> 1) & 3;
    const size_t off = (size_t)t * 262144 + (size_t)(b >> 7) * 8192 + (size_t)(b & 127) * 64;
    const float inv = 127.0f / 8.0f;
    signed char bh[64], bl[64];
#pragma unroll
    for (int k = 0; k < 16; ++k) q2i8(src[k], inv, bh[k], bl[k]);
#pragma unroll
    for (int k = 16; k < 64; ++k) { bh[k] = 0; bl[k] = 0; }
#pragma unroll
    for (int i = 0; i < 4; ++i) {
        *(int4*)(Xh + off + (i ^ sl) * 16) = *(int4*)(bh + i * 16);
        *(int4*)(Xl + off + (i ^ sl) * 16) = *(int4*)(bl + i * 16);
    }
}

__global__ __launch_bounds__(256) void prep_bsum(
    const float* __restrict__ bih, const float* __restrict__ bhh, float* __restrict__ Bsum)
{
    const int id = blockIdx.x * 256 + threadIdx.x;
    if (id >= LL * 2048) return;
    const int l = id >> 11, row = id & 2047;
    const int q = row >> 9, j = row & 511;
    const int np = ((j >> 4) << 6) | (q << 4) | (j & 15);
    Bsum[(size_t)l * 2048 + np] = bih[(size_t)l * 2048 + row] + bhh[(size_t)l * 2048 + row];
}

__global__ __launch_bounds__(256) void prep_fc1t(
    const float* __restrict__ fc1w, float* __restrict__ fc1T)
{
    const int id = blockIdx.x * 256 + threadIdx.x;
    if (id >= 64 * 1536) return;
    const int m = id / 1536, k = id % 1536;
    fc1T[(size_t)k * 64 + m] = fc1w[id];
}

// ---------------- fused diagonal of pipelined split-i8 MFMA LSTM cells -------

struct CellDesc {
    const char* A0h; const char* A0l;
    const char* W0h; const char* W0l;
    const char* A1h; const char* A1l;
    const char* W1h; const char* W1l;
    const float* bsum; const short* Cin;
    char* HoutH; char* HoutL;
    short* Cout; float* Hf32;
    int nk0, aStr0, wStr0, shiftAmt;
};
struct DiagArgs { CellDesc c[3]; };

__global__ __launch_bounds__(256, 4) void lstm_diag(DiagArgs args)
{
    // A-only double-buffered LDS: [buf][digit][4096] = 16KB
    __shared__ char ldsA[2][2][4096];
    const int tid = threadIdx.x;
    const CellDesc d = args.c[blockIdx.x >> 10];
    const int inner = blockIdx.x & 1023;
    // 2D XCD tiling: each XCD covers 16 mhalves x 8 cols (A+B hot in L2)
    const int xcd = inner & 7, q = inner >> 3;         // q: 0..127
    const int mhalf = ((xcd & 3) << 4) | (q & 15);     // 0..63 (64-row slab)
    const int col   = ((xcd >> 2) << 3) | (q >> 4);    // 0..15 (128-np panel)
    const int m0 = mhalf << 6;
    const int mrow = mhalf >> 1;                       // 128-row packed panel
    const int half = mhalf & 1;                        // which 64-row half
    const int lane = tid & 63, wid = tid >> 6;         // wid 0..3
    const int wr = wid >> 1;     // 0..1 (32-row slice)
    const int wc = wid & 1;      // 0..1 (j-block group)
    const int ln = lane & 15, lh = lane >> 4;
    const int sl = (ln >> 1) & 3;          // chunk swizzle (matches prep)

    const int nkTot = d.nk0 + (d.A1h ? 8 : 0);
    // de-phase neighbouring blocks (exact i32 accum => order-free);
    // disabled when shiftAmt needs phase-0-first processing (l==0).
    const int start = (d.shiftAmt == 0) ? ((q & 1) * (nkTot >> 1)) : 0;

    const int lhs = (lh ^ sl) << 4;
    // A fragment offsets within the 4KB half-panel (rows 0..63)
    const int aO0 = (((wr << 5) + (0 << 4) + ln) << 6) + lhs;
    const int aO1 = (((wr << 5) + (1 << 4) + ln) << 6) + lhs;
    // B fragment byte offsets within an 8KB W kstep panel (global reads)
    const int bO0 = (((wc << 6) + (0 << 4) + ln) << 6) + lhs;
    const int bO1 = (((wc << 6) + (1 << 4) + ln) << 6) + lhs;
    const int bO2 = (((wc << 6) + (2 << 4) + ln) << 6) + lhs;
    const int bO3 = (((wc << 6) + (3 << 4) + ln) << 6) + lhs;

    i32x4 accM[2][4], accC[2][4];
#pragma unroll
    for (int m = 0; m < 2; ++m)
#pragma unroll
        for (int n = 0; n < 4; ++n) { accM[m][n] = (i32x4){0,0,0,0}; accC[m][n] = (i32x4){0,0,0,0}; }

    auto stageA = [&](int ks, int buf) {
        const char *pA, *pAl;
        if (ks < d.nk0) {
            const size_t kso = (size_t)ks * 8192 + ((size_t)half << 12);
            pA  = d.A0h + (size_t)mrow * d.aStr0 + kso;
            pAl = d.A0l + (size_t)mrow * d.aStr0 + kso;
        } else {
            const size_t kso = (size_t)(ks - d.nk0) * 8192 + ((size_t)half << 12);
            pA  = d.A1h + (size_t)mrow * 65536 + kso;
            pAl = d.A1l + (size_t)mrow * 65536 + kso;
        }
        const int o = tid << 4;
        gl_lds16(pA  + o, &ldsA[buf][0][0] + o);
        gl_lds16(pAl + o, &ldsA[buf][1][0] + o);
    };
    auto ksAt = [&](int i) { int k = start + i; return (k >= nkTot) ? k - nkTot : k; };

    // prologue: A(0) -> buf0
    stageA(ksAt(0), 0);
    asm volatile("s_waitcnt vmcnt(0)" ::: "memory");
    __builtin_amdgcn_s_barrier();

    for (int i = 0; i < nkTot; ++i) {
        const int ab = i & 1;
        const int ks = ksAt(i);
        // B kstep panel base pointers (wave-uniform -> SGPR)
        const char *pBh, *pBl;
        if (ks < d.nk0) {
            const size_t kso = (size_t)ks * 8192;
            pBh = d.W0h + (size_t)col * d.wStr0 + kso;
            pBl = d.W0l + (size_t)col * d.wStr0 + kso;
        } else {
            const size_t kso = (size_t)(ks - d.nk0) * 8192;
            pBh = d.W1h + (size_t)col * 65536 + kso;
            pBl = d.W1l + (size_t)col * 65536 + kso;
        }
        // issue all B loads up front (L2-resident, coalesced 1KB segments)
        i32x4 b_h0 = *(const i32x4*)(pBh + bO0);
        i32x4 b_l0 = *(const i32x4*)(pBl + bO0);
        i32x4 b_h1 = *(const i32x4*)(pBh + bO1);
        i32x4 b_l1 = *(const i32x4*)(pBl + bO1);
        i32x4 b_h2 = *(const i32x4*)(pBh + bO2);
        i32x4 b_l2 = *(const i32x4*)(pBl + bO2);
        i32x4 b_h3 = *(const i32x4*)(pBh + bO3);
        i32x4 b_l3 = *(const i32x4*)(pBl + bO3);
        // stage next A while B is in flight
        if (i + 1 < nkTot) stageA(ksAt(i + 1), ab ^ 1);

        const char* dA = &ldsA[ab][0][0];
        i32x4 a_h[2], a_l[2];
        a_h[0] = *(const i32x4*)(dA + aO0);
        a_l[0] = *(const i32x4*)(dA + 4096 + aO0);
        a_h[1] = *(const i32x4*)(dA + aO1);
        a_l[1] = *(const i32x4*)(dA + 4096 + aO1);

        __builtin_amdgcn_s_setprio(1);
#pragma unroll
        for (int m = 0; m < 2; ++m) {
            accM[m][0] = __builtin_amdgcn_mfma_i32_16x16x64_i8(a_h[m], b_h0, accM[m][0], 0, 0, 0);
            accC[m][0] = __builtin_amdgcn_mfma_i32_16x16x64_i8(a_h[m], b_l0, accC[m][0], 0, 0, 0);
            accC[m][0] = __builtin_amdgcn_mfma_i32_16x16x64_i8(a_l[m], b_h0, accC[m][0], 0, 0, 0);
        }
#pragma unroll
        for (int m = 0; m < 2; ++m) {
            accM[m][1] = __builtin_amdgcn_mfma_i32_16x16x64_i8(a_h[m], b_h1, accM[m][1], 0, 0, 0);
            accC[m][1] = __builtin_amdgcn_mfma_i32_16x16x64_i8(a_h[m], b_l1, accC[m][1], 0, 0, 0);
            accC[m][1] = __builtin_amdgcn_mfma_i32_16x16x64_i8(a_l[m], b_h1, accC[m][1], 0, 0, 0);
        }
#pragma unroll
        for (int m = 0; m < 2; ++m) {
            accM[m][2] = __builtin_amdgcn_mfma_i32_16x16x64_i8(a_h[m], b_h2, accM[m][2], 0, 0, 0);
            accC[m][2] = __builtin_amdgcn_mfma_i32_16x16x64_i8(a_h[m], b_l2, accC[m][2], 0, 0, 0);
            accC[m][2] = __builtin_amdgcn_mfma_i32_16x16x64_i8(a_l[m], b_h2, accC[m][2], 0, 0, 0);
        }
#pragma unroll
        for (int m = 0; m < 2; ++m) {
            accM[m][3] = __builtin_amdgcn_mfma_i32_16x16x64_i8(a_h[m], b_h3, accM[m][3], 0, 0, 0);
            accC[m][3] = __builtin_amdgcn_mfma_i32_16x16x64_i8(a_h[m], b_l3, accC[m][3], 0, 0, 0);
            accC[m][3] = __builtin_amdgcn_mfma_i32_16x16x64_i8(a_l[m], b_h3, accC[m][3], 0, 0, 0);
        }
        __builtin_amdgcn_s_setprio(0);

        if (d.shiftAmt && ks == d.nk0 - 1) {
#pragma unroll
            for (int m = 0; m < 2; ++m)
#pragma unroll
                for (int n = 0; n < 4; ++n)
#pragma unroll
                    for (int r = 0; r < 4; ++r) {
                        accM[m][n][r] <<= d.shiftAmt;
                        accC[m][n][r] <<= d.shiftAmt;
                    }
        }

        // A-stage(i+1) was issued ~a full kstep ago; drain + barrier ->
        // safe to overwrite buf[ab] (read this kstep) next iteration.
        asm volatile("s_waitcnt vmcnt(0) lgkmcnt(0)" ::: "memory");
        __builtin_amdgcn_s_barrier();
    }

    // lane-local epilogue: frag n == gate q for j = jblk*16 + ln
    const int jblk = (col << 1) + wc;
    const int j = (jblk << 4) + ln;
    const int jk = j & 63;
    float bq[4];
#pragma unroll
    for (int g = 0; g < 4; ++g) bq[g] = d.bsum[(jblk << 6) + (g << 4) + ln];
    const size_t hPan = (size_t)mrow * 65536 + (size_t)(j >> 6) * 8192;
#pragma unroll
    for (int m = 0; m < 2; ++m) {
#pragma unroll
        for (int r = 0; r < 4; ++r) {
            const int b = m0 + (wr << 5) + (m << 4) + (lh << 2) + r;
            const float gi = (float)accM[m][0][r] * GSCALE + (float)accC[m][0][r] * GSCALE_C + bq[0];
            const float gf = (float)accM[m][1][r] * GSCALE + (float)accC[m][1][r] * GSCALE_C + bq[1];
            const float gg = (float)accM[m][2][r] * GSCALE + (float)accC[m][2][r] * GSCALE_C + bq[2];
            const float go = (float)accM[m][3][r] * GSCALE + (float)accC[m][3][r] * GSCALE_C + bq[3];
            const float si = fsig(gi);
            const float sf = fsig(gf);
            const float tg = ftanh(gg);
            const float so = fsig(go);
            const size_t ix = (size_t)b * HH + j;
            const float cp = d.Cin ? (float)d.Cin[ix] * C_INV : 0.f;
            const float c = sf * cp + si * tg;
            const float h = so * ftanh(c);
            d.Cout[ix] = (short)__float2int_rn(c * C_SCALE);
            if (d.Hf32) d.Hf32[ix] = h;
            const float hs = h * 127.f;
            const int ih = __float2int_rn(hs);
            const int il = __float2int_rn((hs - (float)ih) * 128.f);
            const int fb = (((lh << 2) + r) >> 1) & 3;   // = (b>>1)&3
            const size_t ho = hPan + (size_t)(b & 127) * 64 + (size_t)(jk ^ (fb << 4));
            d.HoutH[ho] = (signed char)ih;
            d.HoutL[ho] = (signed char)il;
        }
    }
}

// ---------------- fc head ----------------
__global__ __launch_bounds__(256) void fc1_part_f32(
    const float* __restrict__ Hf,      // [T][B][H] f32 (layer-7 h)
    const float* __restrict__ fc1T, float* __restrict__ midp)
{
    __shared__ float As[32][128];
    __shared__ float Bs[32][64];
    const int tid = threadIdx.x;
    const int b0 = blockIdx.x << 7;
    const int kc = blockIdx.y;
    const int bl = tid & 127, kh = tid >> 7;
    const int mq = tid & 15, rq = tid >> 4;
    float acc[8][4];
#pragma unroll
    for (int r = 0; r < 8; ++r)
#pragma unroll
        for (int c = 0; c < 4; ++c) acc[r][c] = 0.f;

    for (int k0 = 0; k0 < 256; k0 += 32) {
        const int kf = kc * 256 + k0;
        const int tI = kf >> 9, h0 = kf & 511;
        __syncthreads();
        {
            const float* src = Hf + ((size_t)tI * BATCH + b0 + bl) * HH + h0 + (kh << 4);
#pragma unroll
            for (int i = 0; i < 4; ++i) {
                float4 v = *(const float4*)(src + (i << 2));
                As[(kh << 4) + (i << 2) + 0][bl] = v.x;
                As[(kh << 4) + (i << 2) + 1][bl] = v.y;
                As[(kh << 4) + (i << 2) + 2][bl] = v.z;
                As[(kh << 4) + (i << 2) + 3][bl] = v.w;
            }
            const float4* s4 = (const float4*)(fc1T + (size_t)kf * 64);
            float4* d4 = (float4*)(&Bs[0][0]);
            d4[tid] = s4[tid];
            d4[tid + 256] = s4[tid + 256];
        }
        __syncthreads();
#pragma unroll
        for (int kk = 0; kk < 32; ++kk) {
            float a0[4], a1[4], bv[4];
            *(float4*)a0 = *(const float4*)&As[kk][rq << 3];
            *(float4*)a1 = *(const float4*)&As[kk][(rq << 3) + 4];
            *(float4*)bv = *(const float4*)&Bs[kk][mq << 2];
#pragma unroll
            for (int r = 0; r < 4; ++r)
#pragma unroll
                for (int c = 0; c < 4; ++c) {
                    acc[r][c]     += a0[r] * bv[c];
                    acc[r + 4][c] += a1[r] * bv[c];
                }
        }
    }
#pragma unroll
    for (int r = 0; r < 8; ++r) {
        float4 v = make_float4(acc[r][0], acc[r][1], acc[r][2], acc[r][3]);
        *(float4*)(midp + ((size_t)blockIdx.y * BATCH + b0 + (rq << 3) + r) * 64 + (mq << 2)) = v;
    }
}

__global__ __launch_bounds__(256) void fc_red(
    const float* __restrict__ midp, const float* __restrict__ fc1b,
    const float* __restrict__ fc2w, const float* __restrict__ fc2b,
    float* __restrict__ out)
{
    __shared__ float mids[8][64];
    const int tid = threadIdx.x;
    const int b0 = blockIdx.x << 3;
    const int m = tid & 63, rh = tid >> 6;
#pragma unroll
    for (int rr = rh; rr < 8; rr += 4) {
        const int b = b0 + rr;
        float s = fc1b[m];
#pragma unroll
        for (int kc = 0; kc < 6; ++kc) s += midp[((size_t)kc * BATCH + b) * 64 + m];
        mids[rr][m] = s;
    }
    __syncthreads();
    if (tid < 24) {
        const int rr = tid / 3, n = tid % 3;
        float s = fc2b[n];
#pragma unroll
        for (int k = 0; k < 64; ++k) s += mids[rr][k] * fc2w[n * 64 + k];
        out[(size_t)(b0 + rr) * 3 + n] = s;
    }
}

// ---------------- round-1 fp32 fallback ----------------
#define BM 64
#define BJ 64
#define KB 32
#define PAD 4

__global__ __launch_bounds__(256) void lstm_cell(
    const float* __restrict__ Xin, int xin_stride, int Din,
    const float* __restrict__ Wih,
    const float* __restrict__ Hprev,
    const float* __restrict__ Whh,
    const float* __restrict__ bih, const float* __restrict__ bhh,
    const float* __restrict__ Cin,
    float* __restrict__ Hout,
    float* __restrict__ Cout)
{
    __shared__ float As2[KB][BM + PAD];
    __shared__ float Bs2[4][KB][BJ + PAD];
    const int tid = threadIdx.x;
    const int row0 = blockIdx.x * BM;
    const int j0 = blockIdx.y * BJ;
    float acc[8][8];
#pragma unroll
    for (int r = 0; r < 8; ++r)
#pragma unroll
        for (int c = 0; c < 8; ++c) acc[r][c] = 0.f;
    const int tr = tid >> 5;
    const int tc = tid & 31;
    const int tc2 = tc * 2;
    for (int ph = 0; ph < 2; ++ph) {
        const float* Ap; const float* Wp;
        int astr, K, wstr;
        if (ph == 0) { Ap = Xin; astr = xin_stride; K = Din; Wp = Wih; wstr = Din; }
        else { if (Hprev == nullptr) break; Ap = Hprev; astr = HH; K = HH; Wp = Whh; wstr = HH; }
        for (int k0 = 0; k0 < K; k0 += KB) {
            int kw = K - k0; if (kw > KB) kw = KB;
            __syncthreads();
            {
                const int k4 = (tid & 7) * 4;
                const int rb = tid >> 3;
#pragma unroll
                for (int it = 0; it < 2; ++it) {
                    const int r = rb + it * 32;
                    float4 v = make_float4(0.f, 0.f, 0.f, 0.f);
                    if (k4 < kw) v = *(const float4*)(Ap + (size_t)(row0 + r) * astr + k0 + k4);
                    As2[k4 + 0][r] = v.x; As2[k4 + 1][r] = v.y; As2[k4 + 2][r] = v.z; As2[k4 + 3][r] = v.w;
                }
            }
            {
                const int k4 = (tid & 7) * 4;
                const int jb = tid >> 3;
#pragma unroll
                for (int q = 0; q < 4; ++q)
#pragma unroll
                    for (int it = 0; it < 2; ++it) {
                        const int jj = jb + it * 32;
                        float4 v = make_float4(0.f, 0.f, 0.f, 0.f);
                        if (k4 < kw) v = *(const float4*)(Wp + (size_t)(q * HH + j0 + jj) * wstr + k0 + k4);
                        Bs2[q][k4 + 0][jj] = v.x; Bs2[q][k4 + 1][jj] = v.y;
                        Bs2[q][k4 + 2][jj] = v.z; Bs2[q][k4 + 3][jj] = v.w;
                    }
            }
            __syncthreads();
#pragma unroll
            for (int k = 0; k < KB; ++k) {
                float a[8];
                *(float4*)(a) = *(const float4*)&As2[k][tr * 8];
                *(float4*)(a + 4) = *(const float4*)&As2[k][tr * 8 + 4];
#pragma unroll
                for (int q = 0; q < 4; ++q) {
                    const float2 bv = *(const float2*)&Bs2[q][k][tc2];
#pragma unroll
                    for (int r = 0; r < 8; ++r) {
                        acc[r][q * 2 + 0] += a[r] * bv.x;
                        acc[r][q * 2 + 1] += a[r] * bv.y;
                    }
                }
            }
        }
    }
#pragma unroll
    for (int jj = 0; jj < 2; ++jj) {
        const int j = j0 + tc2 + jj;
        const float bi_i = bih[0 * HH + j] + bhh[0 * HH + j];
        const float bi_f = bih[1 * HH + j] + bhh[1 * HH + j];
        const float bi_g = bih[2 * HH + j] + bhh[2 * HH + j];
        const float bi_o = bih[3 * HH + j] + bhh[3 * HH + j];
#pragma unroll
        for (int r = 0; r < 8; ++r) {
            const int b = row0 + tr * 8 + r;
            const float gi = acc[r][0 + jj] + bi_i;
            const float gf = acc[r][2 + jj] + bi_f;
            const float gg = acc[r][4 + jj] + bi_g;
            const float go = acc[r][6 + jj] + bi_o;
            const float i_ = 1.f / (1.f + expf(-gi));
            const float f_ = 1.f / (1.f + expf(-gf));
            const float g_ = tanhf(gg);
            const float o_ = 1.f / (1.f + expf(-go));
            const float cp = Cin ? Cin[(size_t)b * HH + j] : 0.f;
            const float c = f_ * cp + i_ * g_;
            const float h = o_ * tanhf(c);
            Hout[(size_t)b * HH + j] = h;
            Cout[(size_t)b * HH + j] = c;
        }
    }
}

__global__ __launch_bounds__(256) void fc_head(
    const float* __restrict__ hfin,
    const float* __restrict__ fc1w, const float* __restrict__ fc1b,
    const float* __restrict__ fc2w, const float* __restrict__ fc2b,
    float* __restrict__ out)
{
    __shared__ float hrow[4][TT * HH];
    __shared__ float mids[4][64 + 1];
    const int tid = threadIdx.x;
    const int b0 = blockIdx.x * 64;
    for (int it = 0; it < 16; ++it) {
        const int rbase = b0 + it * 4;
        __syncthreads();
        for (int v = tid; v < 1536; v += 256) {
            const int r = v / 384;
            const int k4 = v % 384;
            const int k = k4 * 4;
            const int t = k >> 9;
            const int h = k & 511;
            float4 val = *(const float4*)(hfin + ((size_t)t * BATCH + (rbase + r)) * HH + h);
            *(float4*)&hrow[r][k] = val;
        }
        __syncthreads();
        {
            const int m = tid & 63;
            const int r = tid >> 6;
            float s = fc1b[m];
            const float* wrow = fc1w + (size_t)m * (TT * HH);
            for (int k = 0; k < TT * HH; ++k) s += hrow[r][k] * wrow[k];
            mids[r][m] = s;
        }
        __syncthreads();
        if (tid < 12) {
            const int rr = tid / 3, n = tid % 3;
            float s2 = fc2b[n];
#pragma unroll
            for (int mm = 0; mm < 64; ++mm) s2 += mids[rr][mm] * fc2w[n * 64 + mm];
            out[(size_t)(rbase + rr) * 3 + n] = s2;
        }
    }
}

// ---------------- launch ----------------

extern "C" void kernel_launch(void* const* d_in, const int* in_sizes, int n_in,
                              void* d_out, int out_size, void* d_ws, size_t ws_size,
                              hipStream_t stream) {
    const float* x        = (const float*)d_in[0];
    const float* W_ih0    = (const float*)d_in[1];
    const float* W_ihrest = (const float*)d_in[2];
    const float* W_hh     = (const float*)d_in[3];
    const float* b_ih     = (const float*)d_in[4];
    const float* b_hh     = (const float*)d_in[5];
    const float* fc1w     = (const float*)d_in[6];
    const float* fc1b     = (const float*)d_in[7];
    const float* fc2w     = (const float*)d_in[8];
    const float* fc2b     = (const float*)d_in[9];

    size_t off = 0;
    char* base = (char*)d_ws;
    auto take = [&](size_t bytes) -> void* {
        void* r = base + off;
        off += (bytes + 255) & ~(size_t)255;
        return r;
    };
    char* WihPh = (char*)take(7UL * 1048576);
    char* WihPl = (char*)take(7UL * 1048576);
    char* WhhPh = (char*)take(8UL * 1048576);
    char* WhhPl = (char*)take(8UL * 1048576);
    char* W0Ph  = (char*)take(16UL * 8192);
    char* W0Pl  = (char*)take(16UL * 8192);
    char* XPh   = (char*)take(3UL * 262144);
    char* XPl   = (char*)take(3UL * 262144);
    float* Bsum = (float*)take(8UL * 2048 * 4);
    char *Hh[2], *Hl[2];
    Hh[0] = (char*)take(3UL * 2097152);
    Hl[0] = (char*)take(3UL * 2097152);
    Hh[1] = (char*)take(3UL * 2097152);
    Hl[1] = (char*)take(3UL * 2097152);
    short* Cbuf = (short*)take(8UL * 4096 * 512 * 2);   // per-layer C state (i16)
    float* HfBuf = (float*)take(3UL * 4096 * 512 * 4);
    float* Fc1T = (float*)take(1536UL * 64 * 4);
    float* Midp = (float*)take(6UL * 4096 * 64 * 4);
    const size_t need = off;

    if (ws_size < need) {
        float* ws = (float*)d_ws;
        const size_t hsz = (size_t)TT * BATCH * HH;
        float* hb[2] = { ws, ws + hsz };
        float* cb = ws + 2 * hsz;
        dim3 grid(BATCH / BM, HH / BJ), blk(256);
        for (int l = 0; l < LL; ++l) {
            const float* Wih = (l == 0) ? W_ih0 : W_ihrest + (size_t)(l - 1) * 2048 * HH;
            const float* Whh = W_hh + (size_t)l * 2048 * HH;
            const float* bi = b_ih + l * 2048;
            const float* bh = b_hh + l * 2048;
            float* hout_base = hb[l & 1];
            const float* hin_base = hb[(l + 1) & 1];
            for (int t = 0; t < TT; ++t) {
                const float* Xin; int xstr, Din;
                if (l == 0) { Xin = x + t * 16; xstr = TT * 16; Din = 16; }
                else { Xin = hin_base + (size_t)t * BATCH * HH; xstr = HH; Din = HH; }
                const float* Hprev = (t == 0) ? nullptr : hout_base + (size_t)(t - 1) * BATCH * HH;
                const float* Cin = (t == 0) ? nullptr : cb;
                hipLaunchKernelGGL(lstm_cell, grid, blk, 0, stream,
                    Xin, xstr, Din, Wih, Hprev, Whh, bi, bh, Cin,
                    hout_base + (size_t)t * BATCH * HH, cb);
            }
        }
        fc_head<<<dim3(BATCH / 64), blk, 0, stream>>>(hb[1], fc1w, fc1b, fc2w, fc2b, (float*)d_out);
        return;
    }

    prep_w_i8<<<dim3(15360), dim3(256), 0, stream>>>(W_ihrest, W_hh, WihPh, WihPl, WhhPh, WhhPl);
    prep_w0_i8<<<dim3(8), dim3(256), 0, stream>>>(W_ih0, W0Ph, W0Pl);
    prep_x_i8<<<dim3(48), dim3(256), 0, stream>>>(x, XPh, XPl);
    prep_bsum<<<dim3(64), dim3(256), 0, stream>>>(b_ih, b_hh, Bsum);
    prep_fc1t<<<dim3(384), dim3(256), 0, stream>>>(fc1w, Fc1T);

    // diagonal wavefront: cells (l,t) with l+t = d are independent
    for (int diag = 0; diag <= (LL - 1) + (TT - 1); ++diag) {
        DiagArgs da;
        int nc = 0;
        for (int t = 0; t < TT; ++t) {
            const int l = diag - t;
            if (l < 0 || l >= LL) continue;
            CellDesc cd;
            if (l == 0) {
                cd.A0h = XPh + (size_t)t * 262144; cd.A0l = XPl + (size_t)t * 262144;
                cd.nk0 = 1; cd.aStr0 = 8192;
                cd.W0h = W0Ph; cd.W0l = W0Pl; cd.wStr0 = 8192;
                cd.shiftAmt = 3;
            } else {
                cd.A0h = Hh[(l + 1) & 1] + (size_t)t * 2097152;
                cd.A0l = Hl[(l + 1) & 1] + (size_t)t * 2097152;
                cd.nk0 = 8; cd.aStr0 = 65536;
                cd.W0h = WihPh + (size_t)(l - 1) * 1048576;
                cd.W0l = WihPl + (size_t)(l - 1) * 1048576;
                cd.wStr0 = 65536;
                cd.shiftAmt = 0;
            }
            cd.A1h = (t == 0) ? nullptr : Hh[l & 1] + (size_t)(t - 1) * 2097152;
            cd.A1l = (t == 0) ? nullptr : Hl[l & 1] + (size_t)(t - 1) * 2097152;
            cd.W1h = WhhPh + (size_t)l * 1048576;
            cd.W1l = WhhPl + (size_t)l * 1048576;
            cd.bsum = Bsum + (size_t)l * 2048;
            short* cl = Cbuf + (size_t)l * 2097152;
            cd.Cin = (t == 0) ? nullptr : cl;
            cd.Cout = cl;
            cd.HoutH = Hh[l & 1] + (size_t)t * 2097152;
            cd.HoutL = Hl[l & 1] + (size_t)t * 2097152;
            cd.Hf32 = (l == LL - 1) ? HfBuf + (size_t)t * 2097152 : nullptr;
            da.c[nc++] = cd;
        }
        if (nc) lstm_diag<<<dim3(1024 * nc), dim3(256), 0, stream>>>(da);
    }

    fc1_part_f32<<<dim3(32, 6), dim3(256), 0, stream>>>(HfBuf, Fc1T, Midp);
    fc_red<<<dim3(512), dim3(256), 0, stream>>>(Midp, fc1b, fc2w, fc2b, (float*)d_out);
}

// Round 9
// 465.525 us; speedup vs baseline: 1.3028x; 1.3028x over previous
//
#include <hip/hip_runtime.h>
#include <hip/hip_bf16.h>
#include <math.h>

// LSTM B=4096,T=3,I=16,H=512,L=8 + fc head.
// Round 15 = R12 base (best total) + W single-digit quantization:
//   weights use ONE i8 digit (15-bit pair dropped); gate = ah*bh*GSCALE
//   + al*bh*GSCALE_C + bias. MFMAs per wave-kstep 24 -> 16, B LDS reads
//   and staging halve, W fetch halves. H and X keep 2 digits (recurrence
//   precision preserved). Expected absmax ~5e-4..2e-3 (was 2.44e-4).
// Keeps R12: 2D XCD mapping, A dbuf-2 + B ring-3 (now 56KB), counted
// vmcnt(1), 512-thr/8-wave blocks, 32x64 per wave, bank-swizzled packed
// layout, fast epilogue math, de-phase parity start, setprio.

#define BATCH 4096
#define TT 3
#define HH 512
#define LL 8

typedef __attribute__((ext_vector_type(4))) int   i32x4;

#define S_W 0.04419417382f                  // 1/sqrt(512), weight uniform bound
#define GSCALE   (S_W / 16129.0f)           // sW*sH = (S_W/127)*(1/127)
#define GSCALE_C (GSCALE / 128.0f)
#define C_SCALE   8192.0f
#define C_INV     (1.0f / 8192.0f)

__device__ inline void gl_lds16(const void* g, void* l) {
    __builtin_amdgcn_global_load_lds(
        (const __attribute__((address_space(1))) void*)g,
        (__attribute__((address_space(3))) void*)l, 16, 0, 0);
}

__device__ inline void q2i8(float v, float inv_s, signed char& h, signed char& l) {
    float q = v * inv_s;
    int ih = __float2int_rn(q);
    ih = ih > 127 ? 127 : (ih < -127 ? -127 : ih);
    float rem = q - (float)ih;
    int il = __float2int_rn(rem * 128.f);
    il = il > 127 ? 127 : (il < -127 ? -127 : il);
    h = (signed char)ih; l = (signed char)il;
}

__device__ inline float fsig(float x) {
    return __builtin_amdgcn_rcpf(1.f + __expf(-x));
}
__device__ inline float ftanh(float x) {
    const float e = __expf(-2.f * __builtin_fabsf(x));
    const float t = (1.f - e) * __builtin_amdgcn_rcpf(1.f + e);
    return __builtin_copysignf(t, x);
}

// ---------------- prep kernels ----------------
// Packed layout per matrix digit: [col=np>>7][kstep=k>>6][row=np&127][k&63]
// with 16B chunk c of row r stored at slot c ^ ((r>>1)&3)  (bank swizzle).
// W: single i8 digit (round-to-nearest). X/H: two digits.

__global__ __launch_bounds__(256) void prep_w_i8(
    const float* __restrict__ Wihrest, const float* __restrict__ Whh,
    char* __restrict__ WihPh, char* __restrict__ WhhPh)
{
    const int e = blockIdx.x * 256 + threadIdx.x;   // 15*2048*128 float4 units
    const int mat = e >> 18;
    const int rem = e & 262143;
    const int row = rem >> 7;            // 0..2047
    const int k4  = (rem & 127) << 2;    // 0..508
    const float* src; char *dh;
    if (mat < 7) {
        src = Wihrest + (size_t)mat * 1048576;
        dh = WihPh + (size_t)mat * 1048576;
    } else {
        const int l = mat - 7;
        src = Whh + (size_t)l * 1048576;
        dh = WhhPh + (size_t)l * 1048576;
    }
    const int q = row >> 9, j = row & 511;
    const int np = ((j >> 4) << 6) | (q << 4) | (j & 15);
    const int rw = np & 127;
    const int swz = ((rw >> 1) & 3) << 4;
    const size_t off = (size_t)(np >> 7) * 65536 + (size_t)(k4 >> 6) * 8192
                     + (size_t)rw * 64 + ((k4 & 63) ^ swz);
    const float4 v = *(const float4*)(src + (size_t)row * 512 + k4);
    const float inv = 127.0f / S_W;
    int i0 = __float2int_rn(v.x * inv); i0 = i0 > 127 ? 127 : (i0 < -127 ? -127 : i0);
    int i1 = __float2int_rn(v.y * inv); i1 = i1 > 127 ? 127 : (i1 < -127 ? -127 : i1);
    int i2 = __float2int_rn(v.z * inv); i2 = i2 > 127 ? 127 : (i2 < -127 ? -127 : i2);
    int i3 = __float2int_rn(v.w * inv); i3 = i3 > 127 ? 127 : (i3 < -127 ? -127 : i3);
    unsigned hw = (unsigned char)(signed char)i0 | ((unsigned char)(signed char)i1 << 8) |
                  ((unsigned char)(signed char)i2 << 16) | ((unsigned)(unsigned char)(signed char)i3 << 24);
    *(unsigned*)(dh + off) = hw;
}

__global__ __launch_bounds__(256) void prep_w0_i8(
    const float* __restrict__ W0, char* __restrict__ Dh)
{
    const int row = blockIdx.x * 256 + threadIdx.x;
    if (row >= 2048) return;
    const int q = row >> 9, j = row & 511;
    const int np = ((j >> 4) << 6) | (q << 4) | (j & 15);
    const int sl = (np >> 1) & 3;
    const size_t off = (size_t)(np >> 7) * 8192 + (size_t)(np & 127) * 64;
    const float inv = 127.0f / S_W;
    signed char bh[64];
#pragma unroll
    for (int k = 0; k < 16; ++k) {
        int iv = __float2int_rn(W0[(size_t)row * 16 + k] * inv);
        iv = iv > 127 ? 127 : (iv < -127 ? -127 : iv);
        bh[k] = (signed char)iv;
    }
#pragma unroll
    for (int k = 16; k < 64; ++k) bh[k] = 0;
#pragma unroll
    for (int i = 0; i < 4; ++i) {
        *(int4*)(Dh + off + (i ^ sl) * 16) = *(int4*)(bh + i * 16);
    }
}

__global__ __launch_bounds__(256) void prep_x_i8(
    const float* __restrict__ x, char* __restrict__ Xh, char* __restrict__ Xl)
{
    const int id = blockIdx.x * 256 + threadIdx.x;
    if (id >= TT * BATCH) return;
    const int t = id >> 12, b = id & 4095;
    const float* src = x + ((size_t)b * TT + t) * 16;
    const int sl = (b >> 1) & 3;
    const size_t off = (size_t)t * 262144 + (size_t)(b >> 7) * 8192 + (size_t)(b & 127) * 64;
    const float inv = 127.0f / 8.0f;
    signed char bh[64], bl[64];
#pragma unroll
    for (int k = 0; k < 16; ++k) q2i8(src[k], inv, bh[k], bl[k]);
#pragma unroll
    for (int k = 16; k < 64; ++k) { bh[k] = 0; bl[k] = 0; }
#pragma unroll
    for (int i = 0; i < 4; ++i) {
        *(int4*)(Xh + off + (i ^ sl) * 16) = *(int4*)(bh + i * 16);
        *(int4*)(Xl + off + (i ^ sl) * 16) = *(int4*)(bl + i * 16);
    }
}

__global__ __launch_bounds__(256) void prep_bsum(
    const float* __restrict__ bih, const float* __restrict__ bhh, float* __restrict__ Bsum)
{
    const int id = blockIdx.x * 256 + threadIdx.x;
    if (id >= LL * 2048) return;
    const int l = id >> 11, row = id & 2047;
    const int q = row >> 9, j = row & 511;
    const int np = ((j >> 4) << 6) | (q << 4) | (j & 15);
    Bsum[(size_t)l * 2048 + np] = bih[(size_t)l * 2048 + row] + bhh[(size_t)l * 2048 + row];
}

__global__ __launch_bounds__(256) void prep_fc1t(
    const float* __restrict__ fc1w, float* __restrict__ fc1T)
{
    const int id = blockIdx.x * 256 + threadIdx.x;
    if (id >= 64 * 1536) return;
    const int m = id / 1536, k = id % 1536;
    fc1T[(size_t)k * 64 + m] = fc1w[id];
}

// ---------------- fused diagonal of pipelined split-i8 MFMA LSTM cells -------

struct CellDesc {
    const char* A0h; const char* A0l;
    const char* W0h;
    const char* A1h; const char* A1l;
    const char* W1h;
    const float* bsum; const short* Cin;
    char* HoutH; char* HoutL;
    short* Cout; float* Hf32;
    int nk0, aStr0, wStr0, shiftAmt;
};
struct DiagArgs { CellDesc c[3]; };

__global__ __launch_bounds__(512, 4) void lstm_diag(DiagArgs args)
{
    // A double-buffer (2x2x8KB = 32KB) + B ring-3 single-digit (3x8KB = 24KB)
    __shared__ char ldsA[2][2][8192];
    __shared__ char ldsB[3][8192];
    const int tid = threadIdx.x;
    const CellDesc d = args.c[blockIdx.x >> 9];
    const int inner = blockIdx.x & 511;
    // 2D XCD tiling: each XCD covers 8 mrows x 8 cols -> L2-resident hot set
    const int xcd = inner & 7, q8 = inner >> 3;            // q8: 0..63
    const int mrow = ((xcd & 3) << 3) | (q8 & 7);          // 0..31
    const int col  = ((xcd >> 2) << 3) | (q8 >> 3);        // 0..15
    const int m0 = mrow << 7;
    const int lane = tid & 63, wid = tid >> 6;
    const int wr = wid >> 1;     // 0..3 (32-row slice)
    const int wc = wid & 1;      // 0..1 (j-block group)
    const int ln = lane & 15, lh = lane >> 4;
    const int sl = (ln >> 1) & 3;          // read-side bank swizzle

    const int nkTot = d.nk0 + (d.A1h ? 8 : 0);
    // de-phase neighbouring blocks (exact i32 accum => order-free);
    // disabled when shiftAmt needs phase-0-first processing (l==0).
    const int start = (d.shiftAmt == 0) ? ((q8 & 1) * (nkTot >> 1)) : 0;

    // fragment LDS byte offsets (within an 8KB panel)
    const int lhs = (lh ^ sl) << 4;
    const int aO0 = (((wr << 5) + (0 << 4) + ln) << 6) + lhs;
    const int aO1 = (((wr << 5) + (1 << 4) + ln) << 6) + lhs;
    const int bO0 = (((wc << 6) + (0 << 4) + ln) << 6) + lhs;
    const int bO1 = (((wc << 6) + (1 << 4) + ln) << 6) + lhs;
    const int bO2 = (((wc << 6) + (2 << 4) + ln) << 6) + lhs;
    const int bO3 = (((wc << 6) + (3 << 4) + ln) << 6) + lhs;

    i32x4 accM[2][4], accC[2][4];
#pragma unroll
    for (int m = 0; m < 2; ++m)
#pragma unroll
        for (int n = 0; n < 4; ++n) { accM[m][n] = (i32x4){0,0,0,0}; accC[m][n] = (i32x4){0,0,0,0}; }

    auto stageA = [&](int ks, int buf) {
        const char *pA, *pAl;
        if (ks < d.nk0) {
            const size_t kso = (size_t)ks * 8192;
            pA  = d.A0h + (size_t)mrow * d.aStr0 + kso;
            pAl = d.A0l + (size_t)mrow * d.aStr0 + kso;
        } else {
            const size_t kso = (size_t)(ks - d.nk0) * 8192;
            pA  = d.A1h + (size_t)mrow * 65536 + kso;
            pAl = d.A1l + (size_t)mrow * 65536 + kso;
        }
        const int o = tid << 4;
        gl_lds16(pA  + o, &ldsA[buf][0][0] + o);
        gl_lds16(pAl + o, &ldsA[buf][1][0] + o);
    };
    auto stageB = [&](int ks, int buf) {
        const char *pB;
        if (ks < d.nk0) {
            pB = d.W0h + (size_t)col * d.wStr0 + (size_t)ks * 8192;
        } else {
            pB = d.W1h + (size_t)col * 65536 + (size_t)(ks - d.nk0) * 8192;
        }
        const int o = tid << 4;
        gl_lds16(pB + o, &ldsB[buf][0] + o);
    };
    auto ksAt = [&](int i) { int k = start + i; return (k >= nkTot) ? k - nkTot : k; };

    // prologue: A(0), B(0) -> drain; B(1) stays in flight
    stageA(ksAt(0), 0);
    stageB(ksAt(0), 0);
    if (nkTot > 1) {
        stageB(ksAt(1), 1);
        asm volatile("s_waitcnt vmcnt(1)" ::: "memory");
    } else {
        asm volatile("s_waitcnt vmcnt(0)" ::: "memory");
    }
    __builtin_amdgcn_s_barrier();

    int bb = 0;
    for (int i = 0; i < nkTot; ++i) {
        const int ab = i & 1;
        // issue A(i+1) FIRST, then B(i+2): pre-barrier vmcnt(1) drains
        // A(i+1)+B(i+1), leaves B(i+2) in flight (2-period B window).
        if (i + 1 < nkTot) stageA(ksAt(i + 1), ab ^ 1);
        const bool haveB2 = (i + 2 < nkTot);
        if (haveB2) { int nb = bb + 2; if (nb >= 3) nb -= 3; stageB(ksAt(i + 2), nb); }

        const char* dA = &ldsA[ab][0][0];
        const char* dB = &ldsB[bb][0];
        i32x4 a_h[2], a_l[2];
        a_h[0] = *(const i32x4*)(dA + aO0);
        a_l[0] = *(const i32x4*)(dA + 8192 + aO0);
        a_h[1] = *(const i32x4*)(dA + aO1);
        a_l[1] = *(const i32x4*)(dA + 8192 + aO1);
        i32x4 b_0, b_1, b_2, b_3;
        b_0 = *(const i32x4*)(dB + bO0);
        b_1 = *(const i32x4*)(dB + bO1);
        __builtin_amdgcn_s_setprio(1);
#pragma unroll
        for (int m = 0; m < 2; ++m) {
            accM[m][0] = __builtin_amdgcn_mfma_i32_16x16x64_i8(a_h[m], b_0, accM[m][0], 0, 0, 0);
            accC[m][0] = __builtin_amdgcn_mfma_i32_16x16x64_i8(a_l[m], b_0, accC[m][0], 0, 0, 0);
        }
        b_2 = *(const i32x4*)(dB + bO2);
#pragma unroll
        for (int m = 0; m < 2; ++m) {
            accM[m][1] = __builtin_amdgcn_mfma_i32_16x16x64_i8(a_h[m], b_1, accM[m][1], 0, 0, 0);
            accC[m][1] = __builtin_amdgcn_mfma_i32_16x16x64_i8(a_l[m], b_1, accC[m][1], 0, 0, 0);
        }
        b_3 = *(const i32x4*)(dB + bO3);
#pragma unroll
        for (int m = 0; m < 2; ++m) {
            accM[m][2] = __builtin_amdgcn_mfma_i32_16x16x64_i8(a_h[m], b_2, accM[m][2], 0, 0, 0);
            accC[m][2] = __builtin_amdgcn_mfma_i32_16x16x64_i8(a_l[m], b_2, accC[m][2], 0, 0, 0);
        }
#pragma unroll
        for (int m = 0; m < 2; ++m) {
            accM[m][3] = __builtin_amdgcn_mfma_i32_16x16x64_i8(a_h[m], b_3, accM[m][3], 0, 0, 0);
            accC[m][3] = __builtin_amdgcn_mfma_i32_16x16x64_i8(a_l[m], b_3, accC[m][3], 0, 0, 0);
        }
        __builtin_amdgcn_s_setprio(0);

        if (d.shiftAmt && ksAt(i) == d.nk0 - 1) {
#pragma unroll
            for (int m = 0; m < 2; ++m)
#pragma unroll
                for (int n = 0; n < 4; ++n)
#pragma unroll
                    for (int r = 0; r < 4; ++r) {
                        accM[m][n][r] <<= d.shiftAmt;
                        accC[m][n][r] <<= d.shiftAmt;
                    }
        }

        // counted drain: keep B(i+2) in flight; drain A(i+1), B(i+1), ds_reads
        if (haveB2) { asm volatile("s_waitcnt vmcnt(1) lgkmcnt(0)" ::: "memory"); }
        else        { asm volatile("s_waitcnt vmcnt(0) lgkmcnt(0)" ::: "memory"); }
        __builtin_amdgcn_s_barrier();
        ++bb; if (bb >= 3) bb -= 3;
    }

    // lane-local epilogue: frag n == gate q for j = jblk*16 + ln
    const int jblk = (col << 1) + wc;
    const int j = (jblk << 4) + ln;
    const int jk = j & 63;
    float bq[4];
#pragma unroll
    for (int g = 0; g < 4; ++g) bq[g] = d.bsum[(jblk << 6) + (g << 4) + ln];
    const size_t hPan = (size_t)mrow * 65536 + (size_t)(j >> 6) * 8192;
#pragma unroll
    for (int m = 0; m < 2; ++m) {
#pragma unroll
        for (int r = 0; r < 4; ++r) {
            const int b = m0 + (wr << 5) + (m << 4) + (lh << 2) + r;
            const float gi = (float)accM[m][0][r] * GSCALE + (float)accC[m][0][r] * GSCALE_C + bq[0];
            const float gf = (float)accM[m][1][r] * GSCALE + (float)accC[m][1][r] * GSCALE_C + bq[1];
            const float gg = (float)accM[m][2][r] * GSCALE + (float)accC[m][2][r] * GSCALE_C + bq[2];
            const float go = (float)accM[m][3][r] * GSCALE + (float)accC[m][3][r] * GSCALE_C + bq[3];
            const float si = fsig(gi);
            const float sf = fsig(gf);
            const float tg = ftanh(gg);
            const float so = fsig(go);
            const size_t ix = (size_t)b * HH + j;
            const float cp = d.Cin ? (float)d.Cin[ix] * C_INV : 0.f;
            const float c = sf * cp + si * tg;
            const float h = so * ftanh(c);
            d.Cout[ix] = (short)__float2int_rn(c * C_SCALE);
            if (d.Hf32) d.Hf32[ix] = h;
            const float hs = h * 127.f;
            const int ih = __float2int_rn(hs);
            const int il = __float2int_rn((hs - (float)ih) * 128.f);
            const int fb = (((lh << 2) + r) >> 1) & 3;   // = (b>>1)&3
            const size_t ho = hPan + (size_t)(b & 127) * 64 + (size_t)(jk ^ (fb << 4));
            d.HoutH[ho] = (signed char)ih;
            d.HoutL[ho] = (signed char)il;
        }
    }
}

// ---------------- fc head ----------------
__global__ __launch_bounds__(256) void fc1_part_f32(
    const float* __restrict__ Hf,      // [T][B][H] f32 (layer-7 h)
    const float* __restrict__ fc1T, float* __restrict__ midp)
{
    __shared__ float As[32][128];
    __shared__ float Bs[32][64];
    const int tid = threadIdx.x;
    const int b0 = blockIdx.x << 7;
    const int kc = blockIdx.y;
    const int bl = tid & 127, kh = tid >> 7;
    const int mq = tid & 15, rq = tid >> 4;
    float acc[8][4];
#pragma unroll
    for (int r = 0; r < 8; ++r)
#pragma unroll
        for (int c = 0; c < 4; ++c) acc[r][c] = 0.f;

    for (int k0 = 0; k0 < 256; k0 += 32) {
        const int kf = kc * 256 + k0;
        const int tI = kf >> 9, h0 = kf & 511;
        __syncthreads();
        {
            const float* src = Hf + ((size_t)tI * BATCH + b0 + bl) * HH + h0 + (kh << 4);
#pragma unroll
            for (int i = 0; i < 4; ++i) {
                float4 v = *(const float4*)(src + (i << 2));
                As[(kh << 4) + (i << 2) + 0][bl] = v.x;
                As[(kh << 4) + (i << 2) + 1][bl] = v.y;
                As[(kh << 4) + (i << 2) + 2][bl] = v.z;
                As[(kh << 4) + (i << 2) + 3][bl] = v.w;
            }
            const float4* s4 = (const float4*)(fc1T + (size_t)kf * 64);
            float4* d4 = (float4*)(&Bs[0][0]);
            d4[tid] = s4[tid];
            d4[tid + 256] = s4[tid + 256];
        }
        __syncthreads();
#pragma unroll
        for (int kk = 0; kk < 32; ++kk) {
            float a0[4], a1[4], bv[4];
            *(float4*)a0 = *(const float4*)&As[kk][rq << 3];
            *(float4*)a1 = *(const float4*)&As[kk][(rq << 3) + 4];
            *(float4*)bv = *(const float4*)&Bs[kk][mq << 2];
#pragma unroll
            for (int r = 0; r < 4; ++r)
#pragma unroll
                for (int c = 0; c < 4; ++c) {
                    acc[r][c]     += a0[r] * bv[c];
                    acc[r + 4][c] += a1[r] * bv[c];
                }
        }
    }
#pragma unroll
    for (int r = 0; r < 8; ++r) {
        float4 v = make_float4(acc[r][0], acc[r][1], acc[r][2], acc[r][3]);
        *(float4*)(midp + ((size_t)blockIdx.y * BATCH + b0 + (rq << 3) + r) * 64 + (mq << 2)) = v;
    }
}

__global__ __launch_bounds__(256) void fc_red(
    const float* __restrict__ midp, const float* __restrict__ fc1b,
    const float* __restrict__ fc2w, const float* __restrict__ fc2b,
    float* __restrict__ out)
{
    __shared__ float mids[8][64];
    const int tid = threadIdx.x;
    const int b0 = blockIdx.x << 3;
    const int m = tid & 63, rh = tid >> 6;
#pragma unroll
    for (int rr = rh; rr < 8; rr += 4) {
        const int b = b0 + rr;
        float s = fc1b[m];
#pragma unroll
        for (int kc = 0; kc < 6; ++kc) s += midp[((size_t)kc * BATCH + b) * 64 + m];
        mids[rr][m] = s;
    }
    __syncthreads();
    if (tid < 24) {
        const int rr = tid / 3, n = tid % 3;
        float s = fc2b[n];
#pragma unroll
        for (int k = 0; k < 64; ++k) s += mids[rr][k] * fc2w[n * 64 + k];
        out[(size_t)(b0 + rr) * 3 + n] = s;
    }
}

// ---------------- round-1 fp32 fallback ----------------
#define BM 64
#define BJ 64
#define KB 32
#define PAD 4

__global__ __launch_bounds__(256) void lstm_cell(
    const float* __restrict__ Xin, int xin_stride, int Din,
    const float* __restrict__ Wih,
    const float* __restrict__ Hprev,
    const float* __restrict__ Whh,
    const float* __restrict__ bih, const float* __restrict__ bhh,
    const float* __restrict__ Cin,
    float* __restrict__ Hout,
    float* __restrict__ Cout)
{
    __shared__ float As2[KB][BM + PAD];
    __shared__ float Bs2[4][KB][BJ + PAD];
    const int tid = threadIdx.x;
    const int row0 = blockIdx.x * BM;
    const int j0 = blockIdx.y * BJ;
    float acc[8][8];
#pragma unroll
    for (int r = 0; r < 8; ++r)
#pragma unroll
        for (int c = 0; c < 8; ++c) acc[r][c] = 0.f;
    const int tr = tid >> 5;
    const int tc = tid & 31;
    const int tc2 = tc * 2;
    for (int ph = 0; ph < 2; ++ph) {
        const float* Ap; const float* Wp;
        int astr, K, wstr;
        if (ph == 0) { Ap = Xin; astr = xin_stride; K = Din; Wp = Wih; wstr = Din; }
        else { if (Hprev == nullptr) break; Ap = Hprev; astr = HH; K = HH; Wp = Whh; wstr = HH; }
        for (int k0 = 0; k0 < K; k0 += KB) {
            int kw = K - k0; if (kw > KB) kw = KB;
            __syncthreads();
            {
                const int k4 = (tid & 7) * 4;
                const int rb = tid >> 3;
#pragma unroll
                for (int it = 0; it < 2; ++it) {
                    const int r = rb + it * 32;
                    float4 v = make_float4(0.f, 0.f, 0.f, 0.f);
                    if (k4 < kw) v = *(const float4*)(Ap + (size_t)(row0 + r) * astr + k0 + k4);
                    As2[k4 + 0][r] = v.x; As2[k4 + 1][r] = v.y; As2[k4 + 2][r] = v.z; As2[k4 + 3][r] = v.w;
                }
            }
            {
                const int k4 = (tid & 7) * 4;
                const int jb = tid >> 3;
#pragma unroll
                for (int q = 0; q < 4; ++q)
#pragma unroll
                    for (int it = 0; it < 2; ++it) {
                        const int jj = jb + it * 32;
                        float4 v = make_float4(0.f, 0.f, 0.f, 0.f);
                        if (k4 < kw) v = *(const float4*)(Wp + (size_t)(q * HH + j0 + jj) * wstr + k0 + k4);
                        Bs2[q][k4 + 0][jj] = v.x; Bs2[q][k4 + 1][jj] = v.y;
                        Bs2[q][k4 + 2][jj] = v.z; Bs2[q][k4 + 3][jj] = v.w;
                    }
            }
            __syncthreads();
#pragma unroll
            for (int k = 0; k < KB; ++k) {
                float a[8];
                *(float4*)(a) = *(const float4*)&As2[k][tr * 8];
                *(float4*)(a + 4) = *(const float4*)&As2[k][tr * 8 + 4];
#pragma unroll
                for (int q = 0; q < 4; ++q) {
                    const float2 bv = *(const float2*)&Bs2[q][k][tc2];
#pragma unroll
                    for (int r = 0; r < 8; ++r) {
                        acc[r][q * 2 + 0] += a[r] * bv.x;
                        acc[r][q * 2 + 1] += a[r] * bv.y;
                    }
                }
            }
        }
    }
#pragma unroll
    for (int jj = 0; jj < 2; ++jj) {
        const int j = j0 + tc2 + jj;
        const float bi_i = bih[0 * HH + j] + bhh[0 * HH + j];
        const float bi_f = bih[1 * HH + j] + bhh[1 * HH + j];
        const float bi_g = bih[2 * HH + j] + bhh[2 * HH + j];
        const float bi_o = bih[3 * HH + j] + bhh[3 * HH + j];
#pragma unroll
        for (int r = 0; r < 8; ++r) {
            const int b = row0 + tr * 8 + r;
            const float gi = acc[r][0 + jj] + bi_i;
            const float gf = acc[r][2 + jj] + bi_f;
            const float gg = acc[r][4 + jj] + bi_g;
            const float go = acc[r][6 + jj] + bi_o;
            const float i_ = 1.f / (1.f + expf(-gi));
            const float f_ = 1.f / (1.f + expf(-gf));
            const float g_ = tanhf(gg);
            const float o_ = 1.f / (1.f + expf(-go));
            const float cp = Cin ? Cin[(size_t)b * HH + j] : 0.f;
            const float c = f_ * cp + i_ * g_;
            const float h = o_ * tanhf(c);
            Hout[(size_t)b * HH + j] = h;
            Cout[(size_t)b * HH + j] = c;
        }
    }
}

__global__ __launch_bounds__(256) void fc_head(
    const float* __restrict__ hfin,
    const float* __restrict__ fc1w, const float* __restrict__ fc1b,
    const float* __restrict__ fc2w, const float* __restrict__ fc2b,
    float* __restrict__ out)
{
    __shared__ float hrow[4][TT * HH];
    __shared__ float mids[4][64 + 1];
    const int tid = threadIdx.x;
    const int b0 = blockIdx.x * 64;
    for (int it = 0; it < 16; ++it) {
        const int rbase = b0 + it * 4;
        __syncthreads();
        for (int v = tid; v < 1536; v += 256) {
            const int r = v / 384;
            const int k4 = v % 384;
            const int k = k4 * 4;
            const int t = k >> 9;
            const int h = k & 511;
            float4 val = *(const float4*)(hfin + ((size_t)t * BATCH + (rbase + r)) * HH + h);
            *(float4*)&hrow[r][k] = val;
        }
        __syncthreads();
        {
            const int m = tid & 63;
            const int r = tid >> 6;
            float s = fc1b[m];
            const float* wrow = fc1w + (size_t)m * (TT * HH);
            for (int k = 0; k < TT * HH; ++k) s += hrow[r][k] * wrow[k];
            mids[r][m] = s;
        }
        __syncthreads();
        if (tid < 12) {
            const int rr = tid / 3, n = tid % 3;
            float s2 = fc2b[n];
#pragma unroll
            for (int mm = 0; mm < 64; ++mm) s2 += mids[rr][mm] * fc2w[n * 64 + mm];
            out[(size_t)(rbase + rr) * 3 + n] = s2;
        }
    }
}

// ---------------- launch ----------------

extern "C" void kernel_launch(void* const* d_in, const int* in_sizes, int n_in,
                              void* d_out, int out_size, void* d_ws, size_t ws_size,
                              hipStream_t stream) {
    const float* x        = (const float*)d_in[0];
    const float* W_ih0    = (const float*)d_in[1];
    const float* W_ihrest = (const float*)d_in[2];
    const float* W_hh     = (const float*)d_in[3];
    const float* b_ih     = (const float*)d_in[4];
    const float* b_hh     = (const float*)d_in[5];
    const float* fc1w     = (const float*)d_in[6];
    const float* fc1b     = (const float*)d_in[7];
    const float* fc2w     = (const float*)d_in[8];
    const float* fc2b     = (const float*)d_in[9];

    size_t off = 0;
    char* base = (char*)d_ws;
    auto take = [&](size_t bytes) -> void* {
        void* r = base + off;
        off += (bytes + 255) & ~(size_t)255;
        return r;
    };
    char* WihPh = (char*)take(7UL * 1048576);
    char* WhhPh = (char*)take(8UL * 1048576);
    char* W0Ph  = (char*)take(16UL * 8192);
    char* XPh   = (char*)take(3UL * 262144);
    char* XPl   = (char*)take(3UL * 262144);
    float* Bsum = (float*)take(8UL * 2048 * 4);
    char *Hh[2], *Hl[2];
    Hh[0] = (char*)take(3UL * 2097152);
    Hl[0] = (char*)take(3UL * 2097152);
    Hh[1] = (char*)take(3UL * 2097152);
    Hl[1] = (char*)take(3UL * 2097152);
    short* Cbuf = (short*)take(8UL * 4096 * 512 * 2);   // per-layer C state (i16)
    float* HfBuf = (float*)take(3UL * 4096 * 512 * 4);
    float* Fc1T = (float*)take(1536UL * 64 * 4);
    float* Midp = (float*)take(6UL * 4096 * 64 * 4);
    const size_t need = off;

    if (ws_size < need) {
        float* ws = (float*)d_ws;
        const size_t hsz = (size_t)TT * BATCH * HH;
        float* hb[2] = { ws, ws + hsz };
        float* cb = ws + 2 * hsz;
        dim3 grid(BATCH / BM, HH / BJ), blk(256);
        for (int l = 0; l < LL; ++l) {
            const float* Wih = (l == 0) ? W_ih0 : W_ihrest + (size_t)(l - 1) * 2048 * HH;
            const float* Whh = W_hh + (size_t)l * 2048 * HH;
            const float* bi = b_ih + l * 2048;
            const float* bh = b_hh + l * 2048;
            float* hout_base = hb[l & 1];
            const float* hin_base = hb[(l + 1) & 1];
            for (int t = 0; t < TT; ++t) {
                const float* Xin; int xstr, Din;
                if (l == 0) { Xin = x + t * 16; xstr = TT * 16; Din = 16; }
                else { Xin = hin_base + (size_t)t * BATCH * HH; xstr = HH; Din = HH; }
                const float* Hprev = (t == 0) ? nullptr : hout_base + (size_t)(t - 1) * BATCH * HH;
                const float* Cin = (t == 0) ? nullptr : cb;
                hipLaunchKernelGGL(lstm_cell, grid, blk, 0, stream,
                    Xin, xstr, Din, Wih, Hprev, Whh, bi, bh, Cin,
                    hout_base + (size_t)t * BATCH * HH, cb);
            }
        }
        fc_head<<<dim3(BATCH / 64), blk, 0, stream>>>(hb[1], fc1w, fc1b, fc2w, fc2b, (float*)d_out);
        return;
    }

    prep_w_i8<<<dim3(15360), dim3(256), 0, stream>>>(W_ihrest, W_hh, WihPh, WhhPh);
    prep_w0_i8<<<dim3(8), dim3(256), 0, stream>>>(W_ih0, W0Ph);
    prep_x_i8<<<dim3(48), dim3(256), 0, stream>>>(x, XPh, XPl);
    prep_bsum<<<dim3(64), dim3(256), 0, stream>>>(b_ih, b_hh, Bsum);
    prep_fc1t<<<dim3(384), dim3(256), 0, stream>>>(fc1w, Fc1T);

    // diagonal wavefront: cells (l,t) with l+t = d are independent
    for (int diag = 0; diag <= (LL - 1) + (TT - 1); ++diag) {
        DiagArgs da;
        int nc = 0;
        for (int t = 0; t < TT; ++t) {
            const int l = diag - t;
            if (l < 0 || l >= LL) continue;
            CellDesc cd;
            if (l == 0) {
                cd.A0h = XPh + (size_t)t * 262144; cd.A0l = XPl + (size_t)t * 262144;
                cd.nk0 = 1; cd.aStr0 = 8192;
                cd.W0h = W0Ph; cd.wStr0 = 8192;
                cd.shiftAmt = 3;
            } else {
                cd.A0h = Hh[(l + 1) & 1] + (size_t)t * 2097152;
                cd.A0l = Hl[(l + 1) & 1] + (size_t)t * 2097152;
                cd.nk0 = 8; cd.aStr0 = 65536;
                cd.W0h = WihPh + (size_t)(l - 1) * 1048576;
                cd.wStr0 = 65536;
                cd.shiftAmt = 0;
            }
            cd.A1h = (t == 0) ? nullptr : Hh[l & 1] + (size_t)(t - 1) * 2097152;
            cd.A1l = (t == 0) ? nullptr : Hl[l & 1] + (size_t)(t - 1) * 2097152;
            cd.W1h = WhhPh + (size_t)l * 1048576;
            cd.bsum = Bsum + (size_t)l * 2048;
            short* cl = Cbuf + (size_t)l * 2097152;
            cd.Cin = (t == 0) ? nullptr : cl;
            cd.Cout = cl;
            cd.HoutH = Hh[l & 1] + (size_t)t * 2097152;
            cd.HoutL = Hl[l & 1] + (size_t)t * 2097152;
            cd.Hf32 = (l == LL - 1) ? HfBuf + (size_t)t * 2097152 : nullptr;
            da.c[nc++] = cd;
        }
        if (nc) lstm_diag<<<dim3(512 * nc), dim3(512), 0, stream>>>(da);
    }

    fc1_part_f32<<<dim3(32, 6), dim3(256), 0, stream>>>(HfBuf, Fc1T, Midp);
    fc_red<<<dim3(512), dim3(256), 0, stream>>>(Midp, fc1b, fc2w, fc2b, (float*)d_out);
}

// Round 10
// 318.829 us; speedup vs baseline: 1.9022x; 1.4601x over previous
//
#include <hip/hip_runtime.h>
#include <hip/hip_bf16.h>
#include <math.h>

// LSTM B=4096,T=3,I=16,H=512,L=8 + fc head.
// Round 16 = R15 + A single-digit: gate = ah*bh*GSCALE + bias only.
// R15 proved ~1e-3 gate noise moves absmax by ZERO (W low digit dropped,
// absmax bit-identical) -> drop the symmetric A-side correction too.
// MFMA per wave-kstep 16 -> 8; A staging/LDS reads halve; Hl/Xl buffers,
// their prep and epilogue low-digit stores removed. LDS 40KB/block.
// Keeps R15: 2D XCD mapping, A dbuf-2 + B ring-3, counted vmcnt(1),
// 512-thr/8-wave blocks, 32x64 per wave, bank-swizzled packed layout,
// fast epilogue math, de-phase parity start, setprio.

#define BATCH 4096
#define TT 3
#define HH 512
#define LL 8

typedef __attribute__((ext_vector_type(4))) int   i32x4;

#define S_W 0.04419417382f                  // 1/sqrt(512), weight uniform bound
#define GSCALE   (S_W / 16129.0f)           // sW*sH = (S_W/127)*(1/127)
#define C_SCALE   8192.0f
#define C_INV     (1.0f / 8192.0f)

__device__ inline void gl_lds16(const void* g, void* l) {
    __builtin_amdgcn_global_load_lds(
        (const __attribute__((address_space(1))) void*)g,
        (__attribute__((address_space(3))) void*)l, 16, 0, 0);
}

__device__ inline float fsig(float x) {
    return __builtin_amdgcn_rcpf(1.f + __expf(-x));
}
__device__ inline float ftanh(float x) {
    const float e = __expf(-2.f * __builtin_fabsf(x));
    const float t = (1.f - e) * __builtin_amdgcn_rcpf(1.f + e);
    return __builtin_copysignf(t, x);
}

// ---------------- prep kernels ----------------
// Packed layout per matrix: [col=np>>7][kstep=k>>6][row=np&127][k&63]
// with 16B chunk c of row r stored at slot c ^ ((r>>1)&3)  (bank swizzle).
// All operands single i8 digit (round-to-nearest).

__global__ __launch_bounds__(256) void prep_w_i8(
    const float* __restrict__ Wihrest, const float* __restrict__ Whh,
    char* __restrict__ WihPh, char* __restrict__ WhhPh)
{
    const int e = blockIdx.x * 256 + threadIdx.x;   // 15*2048*128 float4 units
    const int mat = e >> 18;
    const int rem = e & 262143;
    const int row = rem >> 7;            // 0..2047
    const int k4  = (rem & 127) << 2;    // 0..508
    const float* src; char *dh;
    if (mat < 7) {
        src = Wihrest + (size_t)mat * 1048576;
        dh = WihPh + (size_t)mat * 1048576;
    } else {
        const int l = mat - 7;
        src = Whh + (size_t)l * 1048576;
        dh = WhhPh + (size_t)l * 1048576;
    }
    const int q = row >> 9, j = row & 511;
    const int np = ((j >> 4) << 6) | (q << 4) | (j & 15);
    const int rw = np & 127;
    const int swz = ((rw >> 1) & 3) << 4;
    const size_t off = (size_t)(np >> 7) * 65536 + (size_t)(k4 >> 6) * 8192
                     + (size_t)rw * 64 + ((k4 & 63) ^ swz);
    const float4 v = *(const float4*)(src + (size_t)row * 512 + k4);
    const float inv = 127.0f / S_W;
    int i0 = __float2int_rn(v.x * inv); i0 = i0 > 127 ? 127 : (i0 < -127 ? -127 : i0);
    int i1 = __float2int_rn(v.y * inv); i1 = i1 > 127 ? 127 : (i1 < -127 ? -127 : i1);
    int i2 = __float2int_rn(v.z * inv); i2 = i2 > 127 ? 127 : (i2 < -127 ? -127 : i2);
    int i3 = __float2int_rn(v.w * inv); i3 = i3 > 127 ? 127 : (i3 < -127 ? -127 : i3);
    unsigned hw = (unsigned char)(signed char)i0 | ((unsigned char)(signed char)i1 << 8) |
                  ((unsigned char)(signed char)i2 << 16) | ((unsigned)(unsigned char)(signed char)i3 << 24);
    *(unsigned*)(dh + off) = hw;
}

__global__ __launch_bounds__(256) void prep_w0_i8(
    const float* __restrict__ W0, char* __restrict__ Dh)
{
    const int row = blockIdx.x * 256 + threadIdx.x;
    if (row >= 2048) return;
    const int q = row >> 9, j = row & 511;
    const int np = ((j >> 4) << 6) | (q << 4) | (j & 15);
    const int sl = (np >> 1) & 3;
    const size_t off = (size_t)(np >> 7) * 8192 + (size_t)(np & 127) * 64;
    const float inv = 127.0f / S_W;
    signed char bh[64];
#pragma unroll
    for (int k = 0; k < 16; ++k) {
        int iv = __float2int_rn(W0[(size_t)row * 16 + k] * inv);
        iv = iv > 127 ? 127 : (iv < -127 ? -127 : iv);
        bh[k] = (signed char)iv;
    }
#pragma unroll
    for (int k = 16; k < 64; ++k) bh[k] = 0;
#pragma unroll
    for (int i = 0; i < 4; ++i) {
        *(int4*)(Dh + off + (i ^ sl) * 16) = *(int4*)(bh + i * 16);
    }
}

__global__ __launch_bounds__(256) void prep_x_i8(
    const float* __restrict__ x, char* __restrict__ Xh)
{
    const int id = blockIdx.x * 256 + threadIdx.x;
    if (id >= TT * BATCH) return;
    const int t = id >> 12, b = id & 4095;
    const float* src = x + ((size_t)b * TT + t) * 16;
    const int sl = (b >> 1) & 3;
    const size_t off = (size_t)t * 262144 + (size_t)(b >> 7) * 8192 + (size_t)(b & 127) * 64;
    const float inv = 127.0f / 8.0f;
    signed char bh[64];
#pragma unroll
    for (int k = 0; k < 16; ++k) {
        int iv = __float2int_rn(src[k] * inv);
        iv = iv > 127 ? 127 : (iv < -127 ? -127 : iv);
        bh[k] = (signed char)iv;
    }
#pragma unroll
    for (int k = 16; k < 64; ++k) bh[k] = 0;
#pragma unroll
    for (int i = 0; i < 4; ++i) {
        *(int4*)(Xh + off + (i ^ sl) * 16) = *(int4*)(bh + i * 16);
    }
}

__global__ __launch_bounds__(256) void prep_bsum(
    const float* __restrict__ bih, const float* __restrict__ bhh, float* __restrict__ Bsum)
{
    const int id = blockIdx.x * 256 + threadIdx.x;
    if (id >= LL * 2048) return;
    const int l = id >> 11, row = id & 2047;
    const int q = row >> 9, j = row & 511;
    const int np = ((j >> 4) << 6) | (q << 4) | (j & 15);
    Bsum[(size_t)l * 2048 + np] = bih[(size_t)l * 2048 + row] + bhh[(size_t)l * 2048 + row];
}

__global__ __launch_bounds__(256) void prep_fc1t(
    const float* __restrict__ fc1w, float* __restrict__ fc1T)
{
    const int id = blockIdx.x * 256 + threadIdx.x;
    if (id >= 64 * 1536) return;
    const int m = id / 1536, k = id % 1536;
    fc1T[(size_t)k * 64 + m] = fc1w[id];
}

// ---------------- fused diagonal of pipelined i8 MFMA LSTM cells -------

struct CellDesc {
    const char* A0h;
    const char* W0h;
    const char* A1h;
    const char* W1h;
    const float* bsum; const short* Cin;
    char* HoutH;
    short* Cout; float* Hf32;
    int nk0, aStr0, wStr0, shiftAmt;
};
struct DiagArgs { CellDesc c[3]; };

__global__ __launch_bounds__(512, 4) void lstm_diag(DiagArgs args)
{
    // A double-buffer (2x8KB = 16KB) + B ring-3 (3x8KB = 24KB) = 40KB
    __shared__ char ldsA[2][8192];
    __shared__ char ldsB[3][8192];
    const int tid = threadIdx.x;
    const CellDesc d = args.c[blockIdx.x >> 9];
    const int inner = blockIdx.x & 511;
    // 2D XCD tiling: each XCD covers 8 mrows x 8 cols -> L2-resident hot set
    const int xcd = inner & 7, q8 = inner >> 3;            // q8: 0..63
    const int mrow = ((xcd & 3) << 3) | (q8 & 7);          // 0..31
    const int col  = ((xcd >> 2) << 3) | (q8 >> 3);        // 0..15
    const int m0 = mrow << 7;
    const int lane = tid & 63, wid = tid >> 6;
    const int wr = wid >> 1;     // 0..3 (32-row slice)
    const int wc = wid & 1;      // 0..1 (j-block group)
    const int ln = lane & 15, lh = lane >> 4;
    const int sl = (ln >> 1) & 3;          // read-side bank swizzle

    const int nkTot = d.nk0 + (d.A1h ? 8 : 0);
    // de-phase neighbouring blocks (exact i32 accum => order-free);
    // disabled when shiftAmt needs phase-0-first processing (l==0).
    const int start = (d.shiftAmt == 0) ? ((q8 & 1) * (nkTot >> 1)) : 0;

    // fragment LDS byte offsets (within an 8KB panel)
    const int lhs = (lh ^ sl) << 4;
    const int aO0 = (((wr << 5) + (0 << 4) + ln) << 6) + lhs;
    const int aO1 = (((wr << 5) + (1 << 4) + ln) << 6) + lhs;
    const int bO0 = (((wc << 6) + (0 << 4) + ln) << 6) + lhs;
    const int bO1 = (((wc << 6) + (1 << 4) + ln) << 6) + lhs;
    const int bO2 = (((wc << 6) + (2 << 4) + ln) << 6) + lhs;
    const int bO3 = (((wc << 6) + (3 << 4) + ln) << 6) + lhs;

    i32x4 accM[2][4];
#pragma unroll
    for (int m = 0; m < 2; ++m)
#pragma unroll
        for (int n = 0; n < 4; ++n) accM[m][n] = (i32x4){0,0,0,0};

    auto stageA = [&](int ks, int buf) {
        const char *pA;
        if (ks < d.nk0) {
            pA = d.A0h + (size_t)mrow * d.aStr0 + (size_t)ks * 8192;
        } else {
            pA = d.A1h + (size_t)mrow * 65536 + (size_t)(ks - d.nk0) * 8192;
        }
        const int o = tid << 4;
        gl_lds16(pA + o, &ldsA[buf][0] + o);
    };
    auto stageB = [&](int ks, int buf) {
        const char *pB;
        if (ks < d.nk0) {
            pB = d.W0h + (size_t)col * d.wStr0 + (size_t)ks * 8192;
        } else {
            pB = d.W1h + (size_t)col * 65536 + (size_t)(ks - d.nk0) * 8192;
        }
        const int o = tid << 4;
        gl_lds16(pB + o, &ldsB[buf][0] + o);
    };
    auto ksAt = [&](int i) { int k = start + i; return (k >= nkTot) ? k - nkTot : k; };

    // prologue: A(0), B(0) -> drain; B(1) stays in flight
    stageA(ksAt(0), 0);
    stageB(ksAt(0), 0);
    if (nkTot > 1) {
        stageB(ksAt(1), 1);
        asm volatile("s_waitcnt vmcnt(1)" ::: "memory");
    } else {
        asm volatile("s_waitcnt vmcnt(0)" ::: "memory");
    }
    __builtin_amdgcn_s_barrier();

    int bb = 0;
    for (int i = 0; i < nkTot; ++i) {
        const int ab = i & 1;
        // issue A(i+1) FIRST, then B(i+2): pre-barrier vmcnt(1) drains
        // A(i+1)+B(i+1), leaves B(i+2) in flight (2-period B window).
        if (i + 1 < nkTot) stageA(ksAt(i + 1), ab ^ 1);
        const bool haveB2 = (i + 2 < nkTot);
        if (haveB2) { int nb = bb + 2; if (nb >= 3) nb -= 3; stageB(ksAt(i + 2), nb); }

        const char* dA = &ldsA[ab][0];
        const char* dB = &ldsB[bb][0];
        i32x4 a_h[2];
        a_h[0] = *(const i32x4*)(dA + aO0);
        a_h[1] = *(const i32x4*)(dA + aO1);
        i32x4 b_0, b_1, b_2, b_3;
        b_0 = *(const i32x4*)(dB + bO0);
        b_1 = *(const i32x4*)(dB + bO1);
        __builtin_amdgcn_s_setprio(1);
#pragma unroll
        for (int m = 0; m < 2; ++m)
            accM[m][0] = __builtin_amdgcn_mfma_i32_16x16x64_i8(a_h[m], b_0, accM[m][0], 0, 0, 0);
        b_2 = *(const i32x4*)(dB + bO2);
#pragma unroll
        for (int m = 0; m < 2; ++m)
            accM[m][1] = __builtin_amdgcn_mfma_i32_16x16x64_i8(a_h[m], b_1, accM[m][1], 0, 0, 0);
        b_3 = *(const i32x4*)(dB + bO3);
#pragma unroll
        for (int m = 0; m < 2; ++m)
            accM[m][2] = __builtin_amdgcn_mfma_i32_16x16x64_i8(a_h[m], b_2, accM[m][2], 0, 0, 0);
#pragma unroll
        for (int m = 0; m < 2; ++m)
            accM[m][3] = __builtin_amdgcn_mfma_i32_16x16x64_i8(a_h[m], b_3, accM[m][3], 0, 0, 0);
        __builtin_amdgcn_s_setprio(0);

        if (d.shiftAmt && ksAt(i) == d.nk0 - 1) {
#pragma unroll
            for (int m = 0; m < 2; ++m)
#pragma unroll
                for (int n = 0; n < 4; ++n)
#pragma unroll
                    for (int r = 0; r < 4; ++r)
                        accM[m][n][r] <<= d.shiftAmt;
        }

        // counted drain: keep B(i+2) in flight; drain A(i+1), B(i+1), ds_reads
        if (haveB2) { asm volatile("s_waitcnt vmcnt(1) lgkmcnt(0)" ::: "memory"); }
        else        { asm volatile("s_waitcnt vmcnt(0) lgkmcnt(0)" ::: "memory"); }
        __builtin_amdgcn_s_barrier();
        ++bb; if (bb >= 3) bb -= 3;
    }

    // lane-local epilogue: frag n == gate q for j = jblk*16 + ln
    const int jblk = (col << 1) + wc;
    const int j = (jblk << 4) + ln;
    const int jk = j & 63;
    float bq[4];
#pragma unroll
    for (int g = 0; g < 4; ++g) bq[g] = d.bsum[(jblk << 6) + (g << 4) + ln];
    const size_t hPan = (size_t)mrow * 65536 + (size_t)(j >> 6) * 8192;
#pragma unroll
    for (int m = 0; m < 2; ++m) {
#pragma unroll
        for (int r = 0; r < 4; ++r) {
            const int b = m0 + (wr << 5) + (m << 4) + (lh << 2) + r;
            const float gi = (float)accM[m][0][r] * GSCALE + bq[0];
            const float gf = (float)accM[m][1][r] * GSCALE + bq[1];
            const float gg = (float)accM[m][2][r] * GSCALE + bq[2];
            const float go = (float)accM[m][3][r] * GSCALE + bq[3];
            const float si = fsig(gi);
            const float sf = fsig(gf);
            const float tg = ftanh(gg);
            const float so = fsig(go);
            const size_t ix = (size_t)b * HH + j;
            const float cp = d.Cin ? (float)d.Cin[ix] * C_INV : 0.f;
            const float c = sf * cp + si * tg;
            const float h = so * ftanh(c);
            d.Cout[ix] = (short)__float2int_rn(c * C_SCALE);
            if (d.Hf32) d.Hf32[ix] = h;
            const int ih = __float2int_rn(h * 127.f);
            const int fb = (((lh << 2) + r) >> 1) & 3;   // = (b>>1)&3
            const size_t ho = hPan + (size_t)(b & 127) * 64 + (size_t)(jk ^ (fb << 4));
            d.HoutH[ho] = (signed char)ih;
        }
    }
}

// ---------------- fc head ----------------
__global__ __launch_bounds__(256) void fc1_part_f32(
    const float* __restrict__ Hf,      // [T][B][H] f32 (layer-7 h)
    const float* __restrict__ fc1T, float* __restrict__ midp)
{
    __shared__ float As[32][128];
    __shared__ float Bs[32][64];
    const int tid = threadIdx.x;
    const int b0 = blockIdx.x << 7;
    const int kc = blockIdx.y;
    const int bl = tid & 127, kh = tid >> 7;
    const int mq = tid & 15, rq = tid >> 4;
    float acc[8][4];
#pragma unroll
    for (int r = 0; r < 8; ++r)
#pragma unroll
        for (int c = 0; c < 4; ++c) acc[r][c] = 0.f;

    for (int k0 = 0; k0 < 256; k0 += 32) {
        const int kf = kc * 256 + k0;
        const int tI = kf >> 9, h0 = kf & 511;
        __syncthreads();
        {
            const float* src = Hf + ((size_t)tI * BATCH + b0 + bl) * HH + h0 + (kh << 4);
#pragma unroll
            for (int i = 0; i < 4; ++i) {
                float4 v = *(const float4*)(src + (i << 2));
                As[(kh << 4) + (i << 2) + 0][bl] = v.x;
                As[(kh << 4) + (i << 2) + 1][bl] = v.y;
                As[(kh << 4) + (i << 2) + 2][bl] = v.z;
                As[(kh << 4) + (i << 2) + 3][bl] = v.w;
            }
            const float4* s4 = (const float4*)(fc1T + (size_t)kf * 64);
            float4* d4 = (float4*)(&Bs[0][0]);
            d4[tid] = s4[tid];
            d4[tid + 256] = s4[tid + 256];
        }
        __syncthreads();
#pragma unroll
        for (int kk = 0; kk < 32; ++kk) {
            float a0[4], a1[4], bv[4];
            *(float4*)a0 = *(const float4*)&As[kk][rq << 3];
            *(float4*)a1 = *(const float4*)&As[kk][(rq << 3) + 4];
            *(float4*)bv = *(const float4*)&Bs[kk][mq << 2];
#pragma unroll
            for (int r = 0; r < 4; ++r)
#pragma unroll
                for (int c = 0; c < 4; ++c) {
                    acc[r][c]     += a0[r] * bv[c];
                    acc[r + 4][c] += a1[r] * bv[c];
                }
        }
    }
#pragma unroll
    for (int r = 0; r < 8; ++r) {
        float4 v = make_float4(acc[r][0], acc[r][1], acc[r][2], acc[r][3]);
        *(float4*)(midp + ((size_t)blockIdx.y * BATCH + b0 + (rq << 3) + r) * 64 + (mq << 2)) = v;
    }
}

__global__ __launch_bounds__(256) void fc_red(
    const float* __restrict__ midp, const float* __restrict__ fc1b,
    const float* __restrict__ fc2w, const float* __restrict__ fc2b,
    float* __restrict__ out)
{
    __shared__ float mids[8][64];
    const int tid = threadIdx.x;
    const int b0 = blockIdx.x << 3;
    const int m = tid & 63, rh = tid >> 6;
#pragma unroll
    for (int rr = rh; rr < 8; rr += 4) {
        const int b = b0 + rr;
        float s = fc1b[m];
#pragma unroll
        for (int kc = 0; kc < 6; ++kc) s += midp[((size_t)kc * BATCH + b) * 64 + m];
        mids[rr][m] = s;
    }
    __syncthreads();
    if (tid < 24) {
        const int rr = tid / 3, n = tid % 3;
        float s = fc2b[n];
#pragma unroll
        for (int k = 0; k < 64; ++k) s += mids[rr][k] * fc2w[n * 64 + k];
        out[(size_t)(b0 + rr) * 3 + n] = s;
    }
}

// ---------------- round-1 fp32 fallback ----------------
#define BM 64
#define BJ 64
#define KB 32
#define PAD 4

__global__ __launch_bounds__(256) void lstm_cell(
    const float* __restrict__ Xin, int xin_stride, int Din,
    const float* __restrict__ Wih,
    const float* __restrict__ Hprev,
    const float* __restrict__ Whh,
    const float* __restrict__ bih, const float* __restrict__ bhh,
    const float* __restrict__ Cin,
    float* __restrict__ Hout,
    float* __restrict__ Cout)
{
    __shared__ float As2[KB][BM + PAD];
    __shared__ float Bs2[4][KB][BJ + PAD];
    const int tid = threadIdx.x;
    const int row0 = blockIdx.x * BM;
    const int j0 = blockIdx.y * BJ;
    float acc[8][8];
#pragma unroll
    for (int r = 0; r < 8; ++r)
#pragma unroll
        for (int c = 0; c < 8; ++c) acc[r][c] = 0.f;
    const int tr = tid >> 5;
    const int tc = tid & 31;
    const int tc2 = tc * 2;
    for (int ph = 0; ph < 2; ++ph) {
        const float* Ap; const float* Wp;
        int astr, K, wstr;
        if (ph == 0) { Ap = Xin; astr = xin_stride; K = Din; Wp = Wih; wstr = Din; }
        else { if (Hprev == nullptr) break; Ap = Hprev; astr = HH; K = HH; Wp = Whh; wstr = HH; }
        for (int k0 = 0; k0 < K; k0 += KB) {
            int kw = K - k0; if (kw > KB) kw = KB;
            __syncthreads();
            {
                const int k4 = (tid & 7) * 4;
                const int rb = tid >> 3;
#pragma unroll
                for (int it = 0; it < 2; ++it) {
                    const int r = rb + it * 32;
                    float4 v = make_float4(0.f, 0.f, 0.f, 0.f);
                    if (k4 < kw) v = *(const float4*)(Ap + (size_t)(row0 + r) * astr + k0 + k4);
                    As2[k4 + 0][r] = v.x; As2[k4 + 1][r] = v.y; As2[k4 + 2][r] = v.z; As2[k4 + 3][r] = v.w;
                }
            }
            {
                const int k4 = (tid & 7) * 4;
                const int jb = tid >> 3;
#pragma unroll
                for (int q = 0; q < 4; ++q)
#pragma unroll
                    for (int it = 0; it < 2; ++it) {
                        const int jj = jb + it * 32;
                        float4 v = make_float4(0.f, 0.f, 0.f, 0.f);
                        if (k4 < kw) v = *(const float4*)(Wp + (size_t)(q * HH + j0 + jj) * wstr + k0 + k4);
                        Bs2[q][k4 + 0][jj] = v.x; Bs2[q][k4 + 1][jj] = v.y;
                        Bs2[q][k4 + 2][jj] = v.z; Bs2[q][k4 + 3][jj] = v.w;
                    }
            }
            __syncthreads();
#pragma unroll
            for (int k = 0; k < KB; ++k) {
                float a[8];
                *(float4*)(a) = *(const float4*)&As2[k][tr * 8];
                *(float4*)(a + 4) = *(const float4*)&As2[k][tr * 8 + 4];
#pragma unroll
                for (int q = 0; q < 4; ++q) {
                    const float2 bv = *(const float2*)&Bs2[q][k][tc2];
#pragma unroll
                    for (int r = 0; r < 8; ++r) {
                        acc[r][q * 2 + 0] += a[r] * bv.x;
                        acc[r][q * 2 + 1] += a[r] * bv.y;
                    }
                }
            }
        }
    }
#pragma unroll
    for (int jj = 0; jj < 2; ++jj) {
        const int j = j0 + tc2 + jj;
        const float bi_i = bih[0 * HH + j] + bhh[0 * HH + j];
        const float bi_f = bih[1 * HH + j] + bhh[1 * HH + j];
        const float bi_g = bih[2 * HH + j] + bhh[2 * HH + j];
        const float bi_o = bih[3 * HH + j] + bhh[3 * HH + j];
#pragma unroll
        for (int r = 0; r < 8; ++r) {
            const int b = row0 + tr * 8 + r;
            const float gi = acc[r][0 + jj] + bi_i;
            const float gf = acc[r][2 + jj] + bi_f;
            const float gg = acc[r][4 + jj] + bi_g;
            const float go = acc[r][6 + jj] + bi_o;
            const float i_ = 1.f / (1.f + expf(-gi));
            const float f_ = 1.f / (1.f + expf(-gf));
            const float g_ = tanhf(gg);
            const float o_ = 1.f / (1.f + expf(-go));
            const float cp = Cin ? Cin[(size_t)b * HH + j] : 0.f;
            const float c = f_ * cp + i_ * g_;
            const float h = o_ * tanhf(c);
            Hout[(size_t)b * HH + j] = h;
            Cout[(size_t)b * HH + j] = c;
        }
    }
}

__global__ __launch_bounds__(256) void fc_head(
    const float* __restrict__ hfin,
    const float* __restrict__ fc1w, const float* __restrict__ fc1b,
    const float* __restrict__ fc2w, const float* __restrict__ fc2b,
    float* __restrict__ out)
{
    __shared__ float hrow[4][TT * HH];
    __shared__ float mids[4][64 + 1];
    const int tid = threadIdx.x;
    const int b0 = blockIdx.x * 64;
    for (int it = 0; it < 16; ++it) {
        const int rbase = b0 + it * 4;
        __syncthreads();
        for (int v = tid; v < 1536; v += 256) {
            const int r = v / 384;
            const int k4 = v % 384;
            const int k = k4 * 4;
            const int t = k >> 9;
            const int h = k & 511;
            float4 val = *(const float4*)(hfin + ((size_t)t * BATCH + (rbase + r)) * HH + h);
            *(float4*)&hrow[r][k] = val;
        }
        __syncthreads();
        {
            const int m = tid & 63;
            const int r = tid >> 6;
            float s = fc1b[m];
            const float* wrow = fc1w + (size_t)m * (TT * HH);
            for (int k = 0; k < TT * HH; ++k) s += hrow[r][k] * wrow[k];
            mids[r][m] = s;
        }
        __syncthreads();
        if (tid < 12) {
            const int rr = tid / 3, n = tid % 3;
            float s2 = fc2b[n];
#pragma unroll
            for (int mm = 0; mm < 64; ++mm) s2 += mids[rr][mm] * fc2w[n * 64 + mm];
            out[(size_t)(rbase + rr) * 3 + n] = s2;
        }
    }
}

// ---------------- launch ----------------

extern "C" void kernel_launch(void* const* d_in, const int* in_sizes, int n_in,
                              void* d_out, int out_size, void* d_ws, size_t ws_size,
                              hipStream_t stream) {
    const float* x        = (const float*)d_in[0];
    const float* W_ih0    = (const float*)d_in[1];
    const float* W_ihrest = (const float*)d_in[2];
    const float* W_hh     = (const float*)d_in[3];
    const float* b_ih     = (const float*)d_in[4];
    const float* b_hh     = (const float*)d_in[5];
    const float* fc1w     = (const float*)d_in[6];
    const float* fc1b     = (const float*)d_in[7];
    const float* fc2w     = (const float*)d_in[8];
    const float* fc2b     = (const float*)d_in[9];

    size_t off = 0;
    char* base = (char*)d_ws;
    auto take = [&](size_t bytes) -> void* {
        void* r = base + off;
        off += (bytes + 255) & ~(size_t)255;
        return r;
    };
    char* WihPh = (char*)take(7UL * 1048576);
    char* WhhPh = (char*)take(8UL * 1048576);
    char* W0Ph  = (char*)take(16UL * 8192);
    char* XPh   = (char*)take(3UL * 262144);
    float* Bsum = (float*)take(8UL * 2048 * 4);
    char *Hh[2];
    Hh[0] = (char*)take(3UL * 2097152);
    Hh[1] = (char*)take(3UL * 2097152);
    short* Cbuf = (short*)take(8UL * 4096 * 512 * 2);   // per-layer C state (i16)
    float* HfBuf = (float*)take(3UL * 4096 * 512 * 4);
    float* Fc1T = (float*)take(1536UL * 64 * 4);
    float* Midp = (float*)take(6UL * 4096 * 64 * 4);
    const size_t need = off;

    if (ws_size < need) {
        float* ws = (float*)d_ws;
        const size_t hsz = (size_t)TT * BATCH * HH;
        float* hb[2] = { ws, ws + hsz };
        float* cb = ws + 2 * hsz;
        dim3 grid(BATCH / BM, HH / BJ), blk(256);
        for (int l = 0; l < LL; ++l) {
            const float* Wih = (l == 0) ? W_ih0 : W_ihrest + (size_t)(l - 1) * 2048 * HH;
            const float* Whh = W_hh + (size_t)l * 2048 * HH;
            const float* bi = b_ih + l * 2048;
            const float* bh = b_hh + l * 2048;
            float* hout_base = hb[l & 1];
            const float* hin_base = hb[(l + 1) & 1];
            for (int t = 0; t < TT; ++t) {
                const float* Xin; int xstr, Din;
                if (l == 0) { Xin = x + t * 16; xstr = TT * 16; Din = 16; }
                else { Xin = hin_base + (size_t)t * BATCH * HH; xstr = HH; Din = HH; }
                const float* Hprev = (t == 0) ? nullptr : hout_base + (size_t)(t - 1) * BATCH * HH;
                const float* Cin = (t == 0) ? nullptr : cb;
                hipLaunchKernelGGL(lstm_cell, grid, blk, 0, stream,
                    Xin, xstr, Din, Wih, Hprev, Whh, bi, bh, Cin,
                    hout_base + (size_t)t * BATCH * HH, cb);
            }
        }
        fc_head<<<dim3(BATCH / 64), blk, 0, stream>>>(hb[1], fc1w, fc1b, fc2w, fc2b, (float*)d_out);
        return;
    }

    prep_w_i8<<<dim3(15360), dim3(256), 0, stream>>>(W_ihrest, W_hh, WihPh, WhhPh);
    prep_w0_i8<<<dim3(8), dim3(256), 0, stream>>>(W_ih0, W0Ph);
    prep_x_i8<<<dim3(48), dim3(256), 0, stream>>>(x, XPh);
    prep_bsum<<<dim3(64), dim3(256), 0, stream>>>(b_ih, b_hh, Bsum);
    prep_fc1t<<<dim3(384), dim3(256), 0, stream>>>(fc1w, Fc1T);

    // diagonal wavefront: cells (l,t) with l+t = d are independent
    for (int diag = 0; diag <= (LL - 1) + (TT - 1); ++diag) {
        DiagArgs da;
        int nc = 0;
        for (int t = 0; t < TT; ++t) {
            const int l = diag - t;
            if (l < 0 || l >= LL) continue;
            CellDesc cd;
            if (l == 0) {
                cd.A0h = XPh + (size_t)t * 262144;
                cd.nk0 = 1; cd.aStr0 = 8192;
                cd.W0h = W0Ph; cd.wStr0 = 8192;
                cd.shiftAmt = 3;
            } else {
                cd.A0h = Hh[(l + 1) & 1] + (size_t)t * 2097152;
                cd.nk0 = 8; cd.aStr0 = 65536;
                cd.W0h = WihPh + (size_t)(l - 1) * 1048576;
                cd.wStr0 = 65536;
                cd.shiftAmt = 0;
            }
            cd.A1h = (t == 0) ? nullptr : Hh[l & 1] + (size_t)(t - 1) * 2097152;
            cd.W1h = WhhPh + (size_t)l * 1048576;
            cd.bsum = Bsum + (size_t)l * 2048;
            short* cl = Cbuf + (size_t)l * 2097152;
            cd.Cin = (t == 0) ? nullptr : cl;
            cd.Cout = cl;
            cd.HoutH = Hh[l & 1] + (size_t)t * 2097152;
            cd.Hf32 = (l == LL - 1) ? HfBuf + (size_t)t * 2097152 : nullptr;
            da.c[nc++] = cd;
        }
        if (nc) lstm_diag<<<dim3(512 * nc), dim3(512), 0, stream>>>(da);
    }

    fc1_part_f32<<<dim3(32, 6), dim3(256), 0, stream>>>(HfBuf, Fc1T, Midp);
    fc_red<<<dim3(512), dim3(256), 0, stream>>>(Midp, fc1b, fc2w, fc2b, (float*)d_out);
}

// Round 11
// 317.829 us; speedup vs baseline: 1.9082x; 1.0031x over previous
//
#include <hip/hip_runtime.h>
#include <hip/hip_bf16.h>
#include <math.h>

// LSTM B=4096,T=3,I=16,H=512,L=8 + fc head.
// Round 17 = R16 + occupancy doubling: __launch_bounds__(512,8) -> 4 blocks/CU
// (LDS 4x40KB = 160KB exact, VGPR 52 <= 64), 32 waves/CU. De-phase start
// widened to 4-way so co-resident blocks interleave kstep cadences.
// R16 proved single-digit i8 for W AND A leaves absmax bit-identical;
// gate = ah*bh*GSCALE + bias. MFMA 8/wave-kstep, LDS 40KB/block.
// Keeps: 2D XCD mapping, A dbuf-2 + B ring-3, counted vmcnt(1),
// 512-thr/8-wave blocks, 32x64 per wave, bank-swizzled packed layout,
// fast epilogue math, setprio.

#define BATCH 4096
#define TT 3
#define HH 512
#define LL 8

typedef __attribute__((ext_vector_type(4))) int   i32x4;

#define S_W 0.04419417382f                  // 1/sqrt(512), weight uniform bound
#define GSCALE   (S_W / 16129.0f)           // sW*sH = (S_W/127)*(1/127)
#define C_SCALE   8192.0f
#define C_INV     (1.0f / 8192.0f)

__device__ inline void gl_lds16(const void* g, void* l) {
    __builtin_amdgcn_global_load_lds(
        (const __attribute__((address_space(1))) void*)g,
        (__attribute__((address_space(3))) void*)l, 16, 0, 0);
}

__device__ inline float fsig(float x) {
    return __builtin_amdgcn_rcpf(1.f + __expf(-x));
}
__device__ inline float ftanh(float x) {
    const float e = __expf(-2.f * __builtin_fabsf(x));
    const float t = (1.f - e) * __builtin_amdgcn_rcpf(1.f + e);
    return __builtin_copysignf(t, x);
}

// ---------------- prep kernels ----------------
// Packed layout per matrix: [col=np>>7][kstep=k>>6][row=np&127][k&63]
// with 16B chunk c of row r stored at slot c ^ ((r>>1)&3)  (bank swizzle).
// All operands single i8 digit (round-to-nearest).

__global__ __launch_bounds__(256) void prep_w_i8(
    const float* __restrict__ Wihrest, const float* __restrict__ Whh,
    char* __restrict__ WihPh, char* __restrict__ WhhPh)
{
    const int e = blockIdx.x * 256 + threadIdx.x;   // 15*2048*128 float4 units
    const int mat = e >> 18;
    const int rem = e & 262143;
    const int row = rem >> 7;            // 0..2047
    const int k4  = (rem & 127) << 2;    // 0..508
    const float* src; char *dh;
    if (mat < 7) {
        src = Wihrest + (size_t)mat * 1048576;
        dh = WihPh + (size_t)mat * 1048576;
    } else {
        const int l = mat - 7;
        src = Whh + (size_t)l * 1048576;
        dh = WhhPh + (size_t)l * 1048576;
    }
    const int q = row >> 9, j = row & 511;
    const int np = ((j >> 4) << 6) | (q << 4) | (j & 15);
    const int rw = np & 127;
    const int swz = ((rw >> 1) & 3) << 4;
    const size_t off = (size_t)(np >> 7) * 65536 + (size_t)(k4 >> 6) * 8192
                     + (size_t)rw * 64 + ((k4 & 63) ^ swz);
    const float4 v = *(const float4*)(src + (size_t)row * 512 + k4);
    const float inv = 127.0f / S_W;
    int i0 = __float2int_rn(v.x * inv); i0 = i0 > 127 ? 127 : (i0 < -127 ? -127 : i0);
    int i1 = __float2int_rn(v.y * inv); i1 = i1 > 127 ? 127 : (i1 < -127 ? -127 : i1);
    int i2 = __float2int_rn(v.z * inv); i2 = i2 > 127 ? 127 : (i2 < -127 ? -127 : i2);
    int i3 = __float2int_rn(v.w * inv); i3 = i3 > 127 ? 127 : (i3 < -127 ? -127 : i3);
    unsigned hw = (unsigned char)(signed char)i0 | ((unsigned char)(signed char)i1 << 8) |
                  ((unsigned char)(signed char)i2 << 16) | ((unsigned)(unsigned char)(signed char)i3 << 24);
    *(unsigned*)(dh + off) = hw;
}

__global__ __launch_bounds__(256) void prep_w0_i8(
    const float* __restrict__ W0, char* __restrict__ Dh)
{
    const int row = blockIdx.x * 256 + threadIdx.x;
    if (row >= 2048) return;
    const int q = row >> 9, j = row & 511;
    const int np = ((j >> 4) << 6) | (q << 4) | (j & 15);
    const int sl = (np >> 1) & 3;
    const size_t off = (size_t)(np >> 7) * 8192 + (size_t)(np & 127) * 64;
    const float inv = 127.0f / S_W;
    signed char bh[64];
#pragma unroll
    for (int k = 0; k < 16; ++k) {
        int iv = __float2int_rn(W0[(size_t)row * 16 + k] * inv);
        iv = iv > 127 ? 127 : (iv < -127 ? -127 : iv);
        bh[k] = (signed char)iv;
    }
#pragma unroll
    for (int k = 16; k < 64; ++k) bh[k] = 0;
#pragma unroll
    for (int i = 0; i < 4; ++i) {
        *(int4*)(Dh + off + (i ^ sl) * 16) = *(int4*)(bh + i * 16);
    }
}

__global__ __launch_bounds__(256) void prep_x_i8(
    const float* __restrict__ x, char* __restrict__ Xh)
{
    const int id = blockIdx.x * 256 + threadIdx.x;
    if (id >= TT * BATCH) return;
    const int t = id >> 12, b = id & 4095;
    const float* src = x + ((size_t)b * TT + t) * 16;
    const int sl = (b >> 1) & 3;
    const size_t off = (size_t)t * 262144 + (size_t)(b >> 7) * 8192 + (size_t)(b & 127) * 64;
    const float inv = 127.0f / 8.0f;
    signed char bh[64];
#pragma unroll
    for (int k = 0; k < 16; ++k) {
        int iv = __float2int_rn(src[k] * inv);
        iv = iv > 127 ? 127 : (iv < -127 ? -127 : iv);
        bh[k] = (signed char)iv;
    }
#pragma unroll
    for (int k = 16; k < 64; ++k) bh[k] = 0;
#pragma unroll
    for (int i = 0; i < 4; ++i) {
        *(int4*)(Xh + off + (i ^ sl) * 16) = *(int4*)(bh + i * 16);
    }
}

__global__ __launch_bounds__(256) void prep_bsum(
    const float* __restrict__ bih, const float* __restrict__ bhh, float* __restrict__ Bsum)
{
    const int id = blockIdx.x * 256 + threadIdx.x;
    if (id >= LL * 2048) return;
    const int l = id >> 11, row = id & 2047;
    const int q = row >> 9, j = row & 511;
    const int np = ((j >> 4) << 6) | (q << 4) | (j & 15);
    Bsum[(size_t)l * 2048 + np] = bih[(size_t)l * 2048 + row] + bhh[(size_t)l * 2048 + row];
}

__global__ __launch_bounds__(256) void prep_fc1t(
    const float* __restrict__ fc1w, float* __restrict__ fc1T)
{
    const int id = blockIdx.x * 256 + threadIdx.x;
    if (id >= 64 * 1536) return;
    const int m = id / 1536, k = id % 1536;
    fc1T[(size_t)k * 64 + m] = fc1w[id];
}

// ---------------- fused diagonal of pipelined i8 MFMA LSTM cells -------

struct CellDesc {
    const char* A0h;
    const char* W0h;
    const char* A1h;
    const char* W1h;
    const float* bsum; const short* Cin;
    char* HoutH;
    short* Cout; float* Hf32;
    int nk0, aStr0, wStr0, shiftAmt;
};
struct DiagArgs { CellDesc c[3]; };

__global__ __launch_bounds__(512, 8) void lstm_diag(DiagArgs args)
{
    // A double-buffer (2x8KB = 16KB) + B ring-3 (3x8KB = 24KB) = 40KB
    // 4 blocks/CU co-resident (160KB LDS exactly), 32 waves/CU.
    __shared__ char ldsA[2][8192];
    __shared__ char ldsB[3][8192];
    const int tid = threadIdx.x;
    const CellDesc d = args.c[blockIdx.x >> 9];
    const int inner = blockIdx.x & 511;
    // 2D XCD tiling: each XCD covers 8 mrows x 8 cols -> L2-resident hot set
    const int xcd = inner & 7, q8 = inner >> 3;            // q8: 0..63
    const int mrow = ((xcd & 3) << 3) | (q8 & 7);          // 0..31
    const int col  = ((xcd >> 2) << 3) | (q8 >> 3);        // 0..15
    const int m0 = mrow << 7;
    const int lane = tid & 63, wid = tid >> 6;
    const int wr = wid >> 1;     // 0..3 (32-row slice)
    const int wc = wid & 1;      // 0..1 (j-block group)
    const int ln = lane & 15, lh = lane >> 4;
    const int sl = (ln >> 1) & 3;          // read-side bank swizzle

    const int nkTot = d.nk0 + (d.A1h ? 8 : 0);
    // 4-way de-phase of co-resident blocks (exact i32 accum => order-free);
    // disabled when shiftAmt needs phase-0-first processing (l==0).
    const int start = (d.shiftAmt == 0) ? (((q8 & 3) * nkTot) >> 2) : 0;

    // fragment LDS byte offsets (within an 8KB panel)
    const int lhs = (lh ^ sl) << 4;
    const int aO0 = (((wr << 5) + (0 << 4) + ln) << 6) + lhs;
    const int aO1 = (((wr << 5) + (1 << 4) + ln) << 6) + lhs;
    const int bO0 = (((wc << 6) + (0 << 4) + ln) << 6) + lhs;
    const int bO1 = (((wc << 6) + (1 << 4) + ln) << 6) + lhs;
    const int bO2 = (((wc << 6) + (2 << 4) + ln) << 6) + lhs;
    const int bO3 = (((wc << 6) + (3 << 4) + ln) << 6) + lhs;

    i32x4 accM[2][4];
#pragma unroll
    for (int m = 0; m < 2; ++m)
#pragma unroll
        for (int n = 0; n < 4; ++n) accM[m][n] = (i32x4){0,0,0,0};

    auto stageA = [&](int ks, int buf) {
        const char *pA;
        if (ks < d.nk0) {
            pA = d.A0h + (size_t)mrow * d.aStr0 + (size_t)ks * 8192;
        } else {
            pA = d.A1h + (size_t)mrow * 65536 + (size_t)(ks - d.nk0) * 8192;
        }
        const int o = tid << 4;
        gl_lds16(pA + o, &ldsA[buf][0] + o);
    };
    auto stageB = [&](int ks, int buf) {
        const char *pB;
        if (ks < d.nk0) {
            pB = d.W0h + (size_t)col * d.wStr0 + (size_t)ks * 8192;
        } else {
            pB = d.W1h + (size_t)col * 65536 + (size_t)(ks - d.nk0) * 8192;
        }
        const int o = tid << 4;
        gl_lds16(pB + o, &ldsB[buf][0] + o);
    };
    auto ksAt = [&](int i) { int k = start + i; return (k >= nkTot) ? k - nkTot : k; };

    // prologue: A(0), B(0) -> drain; B(1) stays in flight
    stageA(ksAt(0), 0);
    stageB(ksAt(0), 0);
    if (nkTot > 1) {
        stageB(ksAt(1), 1);
        asm volatile("s_waitcnt vmcnt(1)" ::: "memory");
    } else {
        asm volatile("s_waitcnt vmcnt(0)" ::: "memory");
    }
    __builtin_amdgcn_s_barrier();

    int bb = 0;
    for (int i = 0; i < nkTot; ++i) {
        const int ab = i & 1;
        // issue A(i+1) FIRST, then B(i+2): pre-barrier vmcnt(1) drains
        // A(i+1)+B(i+1), leaves B(i+2) in flight (2-period B window).
        if (i + 1 < nkTot) stageA(ksAt(i + 1), ab ^ 1);
        const bool haveB2 = (i + 2 < nkTot);
        if (haveB2) { int nb = bb + 2; if (nb >= 3) nb -= 3; stageB(ksAt(i + 2), nb); }

        const char* dA = &ldsA[ab][0];
        const char* dB = &ldsB[bb][0];
        i32x4 a_h[2];
        a_h[0] = *(const i32x4*)(dA + aO0);
        a_h[1] = *(const i32x4*)(dA + aO1);
        i32x4 b_0, b_1, b_2, b_3;
        b_0 = *(const i32x4*)(dB + bO0);
        b_1 = *(const i32x4*)(dB + bO1);
        __builtin_amdgcn_s_setprio(1);
#pragma unroll
        for (int m = 0; m < 2; ++m)
            accM[m][0] = __builtin_amdgcn_mfma_i32_16x16x64_i8(a_h[m], b_0, accM[m][0], 0, 0, 0);
        b_2 = *(const i32x4*)(dB + bO2);
#pragma unroll
        for (int m = 0; m < 2; ++m)
            accM[m][1] = __builtin_amdgcn_mfma_i32_16x16x64_i8(a_h[m], b_1, accM[m][1], 0, 0, 0);
        b_3 = *(const i32x4*)(dB + bO3);
#pragma unroll
        for (int m = 0; m < 2; ++m)
            accM[m][2] = __builtin_amdgcn_mfma_i32_16x16x64_i8(a_h[m], b_2, accM[m][2], 0, 0, 0);
#pragma unroll
        for (int m = 0; m < 2; ++m)
            accM[m][3] = __builtin_amdgcn_mfma_i32_16x16x64_i8(a_h[m], b_3, accM[m][3], 0, 0, 0);
        __builtin_amdgcn_s_setprio(0);

        if (d.shiftAmt && ksAt(i) == d.nk0 - 1) {
#pragma unroll
            for (int m = 0; m < 2; ++m)
#pragma unroll
                for (int n = 0; n < 4; ++n)
#pragma unroll
                    for (int r = 0; r < 4; ++r)
                        accM[m][n][r] <<= d.shiftAmt;
        }

        // counted drain: keep B(i+2) in flight; drain A(i+1), B(i+1), ds_reads
        if (haveB2) { asm volatile("s_waitcnt vmcnt(1) lgkmcnt(0)" ::: "memory"); }
        else        { asm volatile("s_waitcnt vmcnt(0) lgkmcnt(0)" ::: "memory"); }
        __builtin_amdgcn_s_barrier();
        ++bb; if (bb >= 3) bb -= 3;
    }

    // lane-local epilogue: frag n == gate q for j = jblk*16 + ln
    const int jblk = (col << 1) + wc;
    const int j = (jblk << 4) + ln;
    const int jk = j & 63;
    float bq[4];
#pragma unroll
    for (int g = 0; g < 4; ++g) bq[g] = d.bsum[(jblk << 6) + (g << 4) + ln];
    const size_t hPan = (size_t)mrow * 65536 + (size_t)(j >> 6) * 8192;
#pragma unroll
    for (int m = 0; m < 2; ++m) {
#pragma unroll
        for (int r = 0; r < 4; ++r) {
            const int b = m0 + (wr << 5) + (m << 4) + (lh << 2) + r;
            const float gi = (float)accM[m][0][r] * GSCALE + bq[0];
            const float gf = (float)accM[m][1][r] * GSCALE + bq[1];
            const float gg = (float)accM[m][2][r] * GSCALE + bq[2];
            const float go = (float)accM[m][3][r] * GSCALE + bq[3];
            const float si = fsig(gi);
            const float sf = fsig(gf);
            const float tg = ftanh(gg);
            const float so = fsig(go);
            const size_t ix = (size_t)b * HH + j;
            const float cp = d.Cin ? (float)d.Cin[ix] * C_INV : 0.f;
            const float c = sf * cp + si * tg;
            const float h = so * ftanh(c);
            d.Cout[ix] = (short)__float2int_rn(c * C_SCALE);
            if (d.Hf32) d.Hf32[ix] = h;
            const int ih = __float2int_rn(h * 127.f);
            const int fb = (((lh << 2) + r) >> 1) & 3;   // = (b>>1)&3
            const size_t ho = hPan + (size_t)(b & 127) * 64 + (size_t)(jk ^ (fb << 4));
            d.HoutH[ho] = (signed char)ih;
        }
    }
}

// ---------------- fc head ----------------
__global__ __launch_bounds__(256) void fc1_part_f32(
    const float* __restrict__ Hf,      // [T][B][H] f32 (layer-7 h)
    const float* __restrict__ fc1T, float* __restrict__ midp)
{
    __shared__ float As[32][128];
    __shared__ float Bs[32][64];
    const int tid = threadIdx.x;
    const int b0 = blockIdx.x << 7;
    const int kc = blockIdx.y;
    const int bl = tid & 127, kh = tid >> 7;
    const int mq = tid & 15, rq = tid >> 4;
    float acc[8][4];
#pragma unroll
    for (int r = 0; r < 8; ++r)
#pragma unroll
        for (int c = 0; c < 4; ++c) acc[r][c] = 0.f;

    for (int k0 = 0; k0 < 256; k0 += 32) {
        const int kf = kc * 256 + k0;
        const int tI = kf >> 9, h0 = kf & 511;
        __syncthreads();
        {
            const float* src = Hf + ((size_t)tI * BATCH + b0 + bl) * HH + h0 + (kh << 4);
#pragma unroll
            for (int i = 0; i < 4; ++i) {
                float4 v = *(const float4*)(src + (i << 2));
                As[(kh << 4) + (i << 2) + 0][bl] = v.x;
                As[(kh << 4) + (i << 2) + 1][bl] = v.y;
                As[(kh << 4) + (i << 2) + 2][bl] = v.z;
                As[(kh << 4) + (i << 2) + 3][bl] = v.w;
            }
            const float4* s4 = (const float4*)(fc1T + (size_t)kf * 64);
            float4* d4 = (float4*)(&Bs[0][0]);
            d4[tid] = s4[tid];
            d4[tid + 256] = s4[tid + 256];
        }
        __syncthreads();
#pragma unroll
        for (int kk = 0; kk < 32; ++kk) {
            float a0[4], a1[4], bv[4];
            *(float4*)a0 = *(const float4*)&As[kk][rq << 3];
            *(float4*)a1 = *(const float4*)&As[kk][(rq << 3) + 4];
            *(float4*)bv = *(const float4*)&Bs[kk][mq << 2];
#pragma unroll
            for (int r = 0; r < 4; ++r)
#pragma unroll
                for (int c = 0; c < 4; ++c) {
                    acc[r][c]     += a0[r] * bv[c];
                    acc[r + 4][c] += a1[r] * bv[c];
                }
        }
    }
#pragma unroll
    for (int r = 0; r < 8; ++r) {
        float4 v = make_float4(acc[r][0], acc[r][1], acc[r][2], acc[r][3]);
        *(float4*)(midp + ((size_t)blockIdx.y * BATCH + b0 + (rq << 3) + r) * 64 + (mq << 2)) = v;
    }
}

__global__ __launch_bounds__(256) void fc_red(
    const float* __restrict__ midp, const float* __restrict__ fc1b,
    const float* __restrict__ fc2w, const float* __restrict__ fc2b,
    float* __restrict__ out)
{
    __shared__ float mids[8][64];
    const int tid = threadIdx.x;
    const int b0 = blockIdx.x << 3;
    const int m = tid & 63, rh = tid >> 6;
#pragma unroll
    for (int rr = rh; rr < 8; rr += 4) {
        const int b = b0 + rr;
        float s = fc1b[m];
#pragma unroll
        for (int kc = 0; kc < 6; ++kc) s += midp[((size_t)kc * BATCH + b) * 64 + m];
        mids[rr][m] = s;
    }
    __syncthreads();
    if (tid < 24) {
        const int rr = tid / 3, n = tid % 3;
        float s = fc2b[n];
#pragma unroll
        for (int k = 0; k < 64; ++k) s += mids[rr][k] * fc2w[n * 64 + k];
        out[(size_t)(b0 + rr) * 3 + n] = s;
    }
}

// ---------------- round-1 fp32 fallback ----------------
#define BM 64
#define BJ 64
#define KB 32
#define PAD 4

__global__ __launch_bounds__(256) void lstm_cell(
    const float* __restrict__ Xin, int xin_stride, int Din,
    const float* __restrict__ Wih,
    const float* __restrict__ Hprev,
    const float* __restrict__ Whh,
    const float* __restrict__ bih, const float* __restrict__ bhh,
    const float* __restrict__ Cin,
    float* __restrict__ Hout,
    float* __restrict__ Cout)
{
    __shared__ float As2[KB][BM + PAD];
    __shared__ float Bs2[4][KB][BJ + PAD];
    const int tid = threadIdx.x;
    const int row0 = blockIdx.x * BM;
    const int j0 = blockIdx.y * BJ;
    float acc[8][8];
#pragma unroll
    for (int r = 0; r < 8; ++r)
#pragma unroll
        for (int c = 0; c < 8; ++c) acc[r][c] = 0.f;
    const int tr = tid >> 5;
    const int tc = tid & 31;
    const int tc2 = tc * 2;
    for (int ph = 0; ph < 2; ++ph) {
        const float* Ap; const float* Wp;
        int astr, K, wstr;
        if (ph == 0) { Ap = Xin; astr = xin_stride; K = Din; Wp = Wih; wstr = Din; }
        else { if (Hprev == nullptr) break; Ap = Hprev; astr = HH; K = HH; Wp = Whh; wstr = HH; }
        for (int k0 = 0; k0 < K; k0 += KB) {
            int kw = K - k0; if (kw > KB) kw = KB;
            __syncthreads();
            {
                const int k4 = (tid & 7) * 4;
                const int rb = tid >> 3;
#pragma unroll
                for (int it = 0; it < 2; ++it) {
                    const int r = rb + it * 32;
                    float4 v = make_float4(0.f, 0.f, 0.f, 0.f);
                    if (k4 < kw) v = *(const float4*)(Ap + (size_t)(row0 + r) * astr + k0 + k4);
                    As2[k4 + 0][r] = v.x; As2[k4 + 1][r] = v.y; As2[k4 + 2][r] = v.z; As2[k4 + 3][r] = v.w;
                }
            }
            {
                const int k4 = (tid & 7) * 4;
                const int jb = tid >> 3;
#pragma unroll
                for (int q = 0; q < 4; ++q)
#pragma unroll
                    for (int it = 0; it < 2; ++it) {
                        const int jj = jb + it * 32;
                        float4 v = make_float4(0.f, 0.f, 0.f, 0.f);
                        if (k4 < kw) v = *(const float4*)(Wp + (size_t)(q * HH + j0 + jj) * wstr + k0 + k4);
                        Bs2[q][k4 + 0][jj] = v.x; Bs2[q][k4 + 1][jj] = v.y;
                        Bs2[q][k4 + 2][jj] = v.z; Bs2[q][k4 + 3][jj] = v.w;
                    }
            }
            __syncthreads();
#pragma unroll
            for (int k = 0; k < KB; ++k) {
                float a[8];
                *(float4*)(a) = *(const float4*)&As2[k][tr * 8];
                *(float4*)(a + 4) = *(const float4*)&As2[k][tr * 8 + 4];
#pragma unroll
                for (int q = 0; q < 4; ++q) {
                    const float2 bv = *(const float2*)&Bs2[q][k][tc2];
#pragma unroll
                    for (int r = 0; r < 8; ++r) {
                        acc[r][q * 2 + 0] += a[r] * bv.x;
                        acc[r][q * 2 + 1] += a[r] * bv.y;
                    }
                }
            }
        }
    }
#pragma unroll
    for (int jj = 0; jj < 2; ++jj) {
        const int j = j0 + tc2 + jj;
        const float bi_i = bih[0 * HH + j] + bhh[0 * HH + j];
        const float bi_f = bih[1 * HH + j] + bhh[1 * HH + j];
        const float bi_g = bih[2 * HH + j] + bhh[2 * HH + j];
        const float bi_o = bih[3 * HH + j] + bhh[3 * HH + j];
#pragma unroll
        for (int r = 0; r < 8; ++r) {
            const int b = row0 + tr * 8 + r;
            const float gi = acc[r][0 + jj] + bi_i;
            const float gf = acc[r][2 + jj] + bi_f;
            const float gg = acc[r][4 + jj] + bi_g;
            const float go = acc[r][6 + jj] + bi_o;
            const float i_ = 1.f / (1.f + expf(-gi));
            const float f_ = 1.f / (1.f + expf(-gf));
            const float g_ = tanhf(gg);
            const float o_ = 1.f / (1.f + expf(-go));
            const float cp = Cin ? Cin[(size_t)b * HH + j] : 0.f;
            const float c = f_ * cp + i_ * g_;
            const float h = o_ * tanhf(c);
            Hout[(size_t)b * HH + j] = h;
            Cout[(size_t)b * HH + j] = c;
        }
    }
}

__global__ __launch_bounds__(256) void fc_head(
    const float* __restrict__ hfin,
    const float* __restrict__ fc1w, const float* __restrict__ fc1b,
    const float* __restrict__ fc2w, const float* __restrict__ fc2b,
    float* __restrict__ out)
{
    __shared__ float hrow[4][TT * HH];
    __shared__ float mids[4][64 + 1];
    const int tid = threadIdx.x;
    const int b0 = blockIdx.x * 64;
    for (int it = 0; it < 16; ++it) {
        const int rbase = b0 + it * 4;
        __syncthreads();
        for (int v = tid; v < 1536; v += 256) {
            const int r = v / 384;
            const int k4 = v % 384;
            const int k = k4 * 4;
            const int t = k >> 9;
            const int h = k & 511;
            float4 val = *(const float4*)(hfin + ((size_t)t * BATCH + (rbase + r)) * HH + h);
            *(float4*)&hrow[r][k] = val;
        }
        __syncthreads();
        {
            const int m = tid & 63;
            const int r = tid >> 6;
            float s = fc1b[m];
            const float* wrow = fc1w + (size_t)m * (TT * HH);
            for (int k = 0; k < TT * HH; ++k) s += hrow[r][k] * wrow[k];
            mids[r][m] = s;
        }
        __syncthreads();
        if (tid < 12) {
            const int rr = tid / 3, n = tid % 3;
            float s2 = fc2b[n];
#pragma unroll
            for (int mm = 0; mm < 64; ++mm) s2 += mids[rr][mm] * fc2w[n * 64 + mm];
            out[(size_t)(rbase + rr) * 3 + n] = s2;
        }
    }
}

// ---------------- launch ----------------

extern "C" void kernel_launch(void* const* d_in, const int* in_sizes, int n_in,
                              void* d_out, int out_size, void* d_ws, size_t ws_size,
                              hipStream_t stream) {
    const float* x        = (const float*)d_in[0];
    const float* W_ih0    = (const float*)d_in[1];
    const float* W_ihrest = (const float*)d_in[2];
    const float* W_hh     = (const float*)d_in[3];
    const float* b_ih     = (const float*)d_in[4];
    const float* b_hh     = (const float*)d_in[5];
    const float* fc1w     = (const float*)d_in[6];
    const float* fc1b     = (const float*)d_in[7];
    const float* fc2w     = (const float*)d_in[8];
    const float* fc2b     = (const float*)d_in[9];

    size_t off = 0;
    char* base = (char*)d_ws;
    auto take = [&](size_t bytes) -> void* {
        void* r = base + off;
        off += (bytes + 255) & ~(size_t)255;
        return r;
    };
    char* WihPh = (char*)take(7UL * 1048576);
    char* WhhPh = (char*)take(8UL * 1048576);
    char* W0Ph  = (char*)take(16UL * 8192);
    char* XPh   = (char*)take(3UL * 262144);
    float* Bsum = (float*)take(8UL * 2048 * 4);
    char *Hh[2];
    Hh[0] = (char*)take(3UL * 2097152);
    Hh[1] = (char*)take(3UL * 2097152);
    short* Cbuf = (short*)take(8UL * 4096 * 512 * 2);   // per-layer C state (i16)
    float* HfBuf = (float*)take(3UL * 4096 * 512 * 4);
    float* Fc1T = (float*)take(1536UL * 64 * 4);
    float* Midp = (float*)take(6UL * 4096 * 64 * 4);
    const size_t need = off;

    if (ws_size < need) {
        float* ws = (float*)d_ws;
        const size_t hsz = (size_t)TT * BATCH * HH;
        float* hb[2] = { ws, ws + hsz };
        float* cb = ws + 2 * hsz;
        dim3 grid(BATCH / BM, HH / BJ), blk(256);
        for (int l = 0; l < LL; ++l) {
            const float* Wih = (l == 0) ? W_ih0 : W_ihrest + (size_t)(l - 1) * 2048 * HH;
            const float* Whh = W_hh + (size_t)l * 2048 * HH;
            const float* bi = b_ih + l * 2048;
            const float* bh = b_hh + l * 2048;
            float* hout_base = hb[l & 1];
            const float* hin_base = hb[(l + 1) & 1];
            for (int t = 0; t < TT; ++t) {
                const float* Xin; int xstr, Din;
                if (l == 0) { Xin = x + t * 16; xstr = TT * 16; Din = 16; }
                else { Xin = hin_base + (size_t)t * BATCH * HH; xstr = HH; Din = HH; }
                const float* Hprev = (t == 0) ? nullptr : hout_base + (size_t)(t - 1) * BATCH * HH;
                const float* Cin = (t == 0) ? nullptr : cb;
                hipLaunchKernelGGL(lstm_cell, grid, blk, 0, stream,
                    Xin, xstr, Din, Wih, Hprev, Whh, bi, bh, Cin,
                    hout_base + (size_t)t * BATCH * HH, cb);
            }
        }
        fc_head<<<dim3(BATCH / 64), blk, 0, stream>>>(hb[1], fc1w, fc1b, fc2w, fc2b, (float*)d_out);
        return;
    }

    prep_w_i8<<<dim3(15360), dim3(256), 0, stream>>>(W_ihrest, W_hh, WihPh, WhhPh);
    prep_w0_i8<<<dim3(8), dim3(256), 0, stream>>>(W_ih0, W0Ph);
    prep_x_i8<<<dim3(48), dim3(256), 0, stream>>>(x, XPh);
    prep_bsum<<<dim3(64), dim3(256), 0, stream>>>(b_ih, b_hh, Bsum);
    prep_fc1t<<<dim3(384), dim3(256), 0, stream>>>(fc1w, Fc1T);

    // diagonal wavefront: cells (l,t) with l+t = d are independent
    for (int diag = 0; diag <= (LL - 1) + (TT - 1); ++diag) {
        DiagArgs da;
        int nc = 0;
        for (int t = 0; t < TT; ++t) {
            const int l = diag - t;
            if (l < 0 || l >= LL) continue;
            CellDesc cd;
            if (l == 0) {
                cd.A0h = XPh + (size_t)t * 262144;
                cd.nk0 = 1; cd.aStr0 = 8192;
                cd.W0h = W0Ph; cd.wStr0 = 8192;
                cd.shiftAmt = 3;
            } else {
                cd.A0h = Hh[(l + 1) & 1] + (size_t)t * 2097152;
                cd.nk0 = 8; cd.aStr0 = 65536;
                cd.W0h = WihPh + (size_t)(l - 1) * 1048576;
                cd.wStr0 = 65536;
                cd.shiftAmt = 0;
            }
            cd.A1h = (t == 0) ? nullptr : Hh[l & 1] + (size_t)(t - 1) * 2097152;
            cd.W1h = WhhPh + (size_t)l * 1048576;
            cd.bsum = Bsum + (size_t)l * 2048;
            short* cl = Cbuf + (size_t)l * 2097152;
            cd.Cin = (t == 0) ? nullptr : cl;
            cd.Cout = cl;
            cd.HoutH = Hh[l & 1] + (size_t)t * 2097152;
            cd.Hf32 = (l == LL - 1) ? HfBuf + (size_t)t * 2097152 : nullptr;
            da.c[nc++] = cd;
        }
        if (nc) lstm_diag<<<dim3(512 * nc), dim3(512), 0, stream>>>(da);
    }

    fc1_part_f32<<<dim3(32, 6), dim3(256), 0, stream>>>(HfBuf, Fc1T, Midp);
    fc_red<<<dim3(512), dim3(256), 0, stream>>>(Midp, fc1b, fc2w, fc2b, (float*)d_out);
}